// Round 11
// baseline (206.408 us; speedup 1.0000x reference)
//
#include <hip/hip_runtime.h>
#include <math.h>

#define DEVFN static __device__ __forceinline__

static constexpr int BB = 8, VV = 13, HH = 32, WW = 64;
static constexpr int NPLANE = HH * WW;        // 2048
static constexpr int NF = BB * VV * NPLANE;   // 212992
static constexpr int NHB = BB * 65 * NPLANE;  // 1064960

static constexpr float DT = 300.0f;
static constexpr float KHc = 15.0f, KVc = 0.1f;
static constexpr float OMEGAc = 7.29e-5f;
static constexpr float L_Vc = 2.5e6f;
static constexpr float R_GASc = 8.314f;
static constexpr float C_Pc = 1005.0f;
static constexpr float PTHc = 0.8f;
static constexpr float PYc  = (float)(3.14159265358979323846 * 6371000.0 / 33.0);
static constexpr float PXCc = (float)(2.0 * 3.14159265358979323846 * 6371000.0 / 64.0);
static constexpr double RCCd = 0.7 * 5.67e-8 * 287.0 / (1005.0 * 100.0);
static constexpr float FBIG = 3.402823466e38f;

__constant__ float cDZ[13]  = {50,50,50,50,50,75,100,100,100,125,112,75,75};
// (1/12)/dz
__constant__ float cZI[13] = {
  (float)(1.0/600.0), (float)(1.0/600.0), (float)(1.0/600.0), (float)(1.0/600.0), (float)(1.0/600.0),
  (float)(1.0/900.0), (float)(1.0/1200.0), (float)(1.0/1200.0), (float)(1.0/1200.0),
  (float)(1.0/1500.0), (float)(1.0/1344.0), (float)(1.0/900.0), (float)(1.0/900.0)};
// -RCC/pressure
__constant__ float cRC[13] = {
  (float)(-RCCd/50.0), (float)(-RCCd/100.0), (float)(-RCCd/150.0), (float)(-RCCd/200.0),
  (float)(-RCCd/250.0), (float)(-RCCd/300.0), (float)(-RCCd/400.0), (float)(-RCCd/500.0),
  (float)(-RCCd/600.0), (float)(-RCCd/700.0), (float)(-RCCd/850.0), (float)(-RCCd/925.0),
  (float)(-RCCd/1000.0)};
// dz * (-R_GAS/pressure)
__constant__ float cZW[13] = {
  (float)(50.0*(-8.314/50.0)), (float)(50.0*(-8.314/100.0)), (float)(50.0*(-8.314/150.0)),
  (float)(50.0*(-8.314/200.0)), (float)(50.0*(-8.314/250.0)), (float)(75.0*(-8.314/300.0)),
  (float)(100.0*(-8.314/400.0)), (float)(100.0*(-8.314/500.0)), (float)(100.0*(-8.314/600.0)),
  (float)(125.0*(-8.314/700.0)), (float)(112.0*(-8.314/850.0)), (float)(75.0*(-8.314/925.0)),
  (float)(75.0*(-8.314/1000.0))};

typedef short bf16x8 __attribute__((ext_vector_type(8)));
typedef float f32x4 __attribute__((ext_vector_type(4)));

DEVFN int pmh(int r){ return r < 0 ? r + 2 : (r > HH - 1 ? r - 2 : r); }
DEVFN int pmv(int r){ return r < 0 ? r + 2 : (r > VV - 1 ? r - 2 : r); }
DEVFN float latOf(int h){ return (90.0f - (float)(h + 1) * (180.0f / 33.0f)) * 0.017453292519943295f; }
DEVFN float avoid_inf(float t){
  if (t == 0.0f) t = 0.1f;
  if (fabsf(t) < 1.0f) t = copysignf(1.0f, t);
  return t;
}
DEVFN unsigned short f2bf(float f){
  unsigned u = __float_as_uint(f);
  unsigned r = (u + 0x7fffu + ((u >> 16) & 1u)) >> 16;
  return (unsigned short)r;
}

// ---- global-memory stencils on [B][13][32][64] ----
DEVFN float d_xf(const float* __restrict__ F, int rb, int w, float invpx){
  return (F[rb + ((w + 62) & 63)] - 8.f * F[rb + ((w + 63) & 63)]
        + 8.f * F[rb + ((w + 1) & 63)] - F[rb + ((w + 2) & 63)]) * (1.f / 12.f) * invpx;
}
DEVFN float d_yf(const float* __restrict__ F, int bvbase, int h, int w){
  return (-F[bvbase + pmh(h - 2) * 64 + w] + 8.f * F[bvbase + pmh(h - 1) * 64 + w]
          - 8.f * F[bvbase + pmh(h + 1) * 64 + w] + F[bvbase + pmh(h + 2) * 64 + w]) * (1.f / 12.f) * (1.f / PYc);
}
DEVFN float d_zf(const float* __restrict__ F, int bbase, int v, int hw){
  return (-F[bbase + pmv(v - 2) * 2048 + hw] + 8.f * F[bbase + pmv(v - 1) * 2048 + hw]
          - 8.f * F[bbase + pmv(v + 1) * 2048 + hw] + F[bbase + pmv(v + 2) * 2048 + hw]) * cZI[v];
}
DEVFN float dxxf(const float* __restrict__ F, int rb, int w, float invpx){
  float s = F[rb + ((w + 60) & 63)] - 16.f * F[rb + ((w + 61) & 63)] + 64.f * F[rb + ((w + 62) & 63)]
          + 16.f * F[rb + ((w + 63) & 63)] - 130.f * F[rb + w] + 16.f * F[rb + ((w + 1) & 63)]
          + 64.f * F[rb + ((w + 2) & 63)] - 16.f * F[rb + ((w + 3) & 63)] + F[rb + ((w + 4) & 63)];
  return s * (1.f / 144.f) * invpx * invpx;
}
DEVFN float dyyf(const float* __restrict__ F, int bvbase, int h, int w){
  float g0 = d_yf(F, bvbase, pmh(h - 2), w);
  float g1 = d_yf(F, bvbase, pmh(h - 1), w);
  float g2 = d_yf(F, bvbase, pmh(h + 1), w);
  float g3 = d_yf(F, bvbase, pmh(h + 2), w);
  return (-g0 + 8.f * g1 - 8.f * g2 + g3) * (1.f / 12.f) * (1.f / PYc);
}
DEVFN float dzzf(const float* __restrict__ F, int bbase, int v, int hw){
  float g0 = d_zf(F, bbase, pmv(v - 2), hw);
  float g1 = d_zf(F, bbase, pmv(v - 1), hw);
  float g2 = d_zf(F, bbase, pmv(v + 1), hw);
  float g3 = d_zf(F, bbase, pmv(v + 2), hw);
  return (-g0 + 8.f * g1 - 8.f * g2 + g3) * cZI[v];
}

// ---- reductions ----
DEVFN float waveRedSum(float v){ for (int o = 32; o; o >>= 1) v += __shfl_down(v, o, 64); return v; }
DEVFN float waveRedMin(float v){ for (int o = 32; o; o >>= 1) v = fminf(v, __shfl_down(v, o, 64)); return v; }
DEVFN float waveRedMax(float v){ for (int o = 32; o; o >>= 1) v = fmaxf(v, __shfl_down(v, o, 64)); return v; }

template<int OP, int NWV>
static __device__ float blockRedN(float v){
  __shared__ float s[NWV];
  v = OP == 0 ? waveRedSum(v) : OP == 1 ? waveRedMin(v) : waveRedMax(v);
  int lane = threadIdx.x & 63, wid = threadIdx.x >> 6;
  __syncthreads();
  if (lane == 0) s[wid] = v;
  __syncthreads();
  float r = s[0];
  #pragma unroll
  for (int k = 1; k < NWV; ++k)
    r = OP == 0 ? r + s[k] : OP == 1 ? fminf(r, s[k]) : fmaxf(r, s[k]);
  return r;
}

struct GB { const float* g[5]; const float* b[5]; };

// ================= launch 1: transpose x + pack both weights =================
__global__ void __launch_bounds__(256) pre_k(const float* __restrict__ x,
    const float* __restrict__ w1, const float* __restrict__ w2,
    unsigned short* __restrict__ XT, unsigned short* __restrict__ wp1,
    unsigned short* __restrict__ wp2)
{
  int blk = blockIdx.x, t = threadIdx.x;
  if (blk < 2048){
    __shared__ float tile[16 * 68];
    int zz = blk >> 8, rem = blk & 255;
    int b = rem >> 5, h = rem & 31;
    for (int p = zz * 2; p < zz * 2 + 2; ++p){
      int cbase = p * 16;
      __syncthreads();
      {
        int cl = t >> 4, w4 = (t & 15) * 4;
        float4 v = *(const float4*)(x + (((size_t)(b * 256 + cbase + cl) * 32 + h) * 64 + w4));
        tile[cl * 68 + w4 + 0] = v.x; tile[cl * 68 + w4 + 1] = v.y;
        tile[cl * 68 + w4 + 2] = v.z; tile[cl * 68 + w4 + 3] = v.w;
      }
      __syncthreads();
      {
        int w = t >> 2, c4 = (t & 3) * 4;
        ushort4 o;
        o.x = f2bf(tile[(c4 + 0) * 68 + w]);
        o.y = f2bf(tile[(c4 + 1) * 68 + w]);
        o.z = f2bf(tile[(c4 + 2) * 68 + w]);
        o.w = f2bf(tile[(c4 + 3) * 68 + w]);
        *(ushort4*)(XT + (((size_t)(b * 32 + h) * 64 + w) * 256 + cbase + c4)) = o;
      }
    }
  } else {
    const int T1 = 9 * 80 * 256;
    const int T2 = 9 * 256 * 96;
    int idx = (blk - 2048) * 256 + t;
    if (idx < T1){
      int dir = idx / (80 * 256);
      int r = idx - dir * (80 * 256);
      int co = r / 256, ci = r - co * 256;
      float v = (co < 65) ? w1[((size_t)(co * 256 + ci)) * 9 + dir] : 0.f;
      wp1[idx] = f2bf(v);
    } else if (idx < T1 + T2){
      int j = idx - T1;
      int dir = j / (256 * 96);
      int r = j - dir * (256 * 96);
      int co = r / 96, ci = r - co * 96;
      float v = (ci < 65) ? w2[((size_t)(co * 65 + ci)) * 9 + dir] : 0.f;
      wp2[j] = f2bf(v);
    }
  }
}

// ================= conv via MFMA; 32-pixel blocks; BN partials in epilogue =================
template<int CIT, int CIL, int CO, int COp, int NW, int MF, int SWZ>
__global__ void __launch_bounds__(NW * 64) conv_mfma_k(
    const unsigned short* __restrict__ XT, const unsigned short* __restrict__ Wp,
    const float* __restrict__ bias, float* __restrict__ out, float* __restrict__ bnp)
{
  __shared__ __align__(16) unsigned short Xl[3 * 34 * CIL];
  const int C8 = CIL / 8;
  int tid = threadIdx.x;
  int bx = blockIdx.x, b = blockIdx.y;
  int h = bx >> 1, p0 = (bx & 1) << 5;
  int bh = b * 64 + bx;
  int wid = tid >> 6, lane = tid & 63;
  int l15 = lane & 15, q = lane >> 4;

  f32x4 acc[MF][2];
  #pragma unroll
  for (int mf = 0; mf < MF; ++mf)
    #pragma unroll
    for (int nf = 0; nf < 2; ++nf){ f32x4 z = {0.f, 0.f, 0.f, 0.f}; acc[mf][nf] = z; }

  for (int cp = 0; cp < CIT / CIL; ++cp){
    if (cp) __syncthreads();
    for (int idx = tid; idx < 3 * 34 * C8; idx += NW * 64){
      int r = idx / (34 * C8);
      int rest = idx - r * (34 * C8);
      int j = rest / C8;
      int c8 = rest - j * C8;
      int hh = h + r - 1;
      int gw = p0 - 1 + j;
      uint4 val = make_uint4(0, 0, 0, 0);
      if (hh >= 0 && hh < 32 && gw >= 0 && gw < 64)
        val = *(const uint4*)(XT + (((size_t)(b * 32 + hh) * 64 + gw) * CIT + cp * CIL + c8 * 8));
      int dst = (r * 34 + j) * CIL + ((c8 * 8) ^ ((j & SWZ) << 3));
      *(uint4*)(Xl + dst) = val;
    }
    __syncthreads();

    for (int dir = 0; dir < 9; ++dir){
      int dy = dir / 3, dx = dir - dy * 3;
      #pragma unroll
      for (int kc = 0; kc < CIL / 32; ++kc){
        int kb = kc * 32 + q * 8;
        bf16x8 a[MF];
        #pragma unroll
        for (int mf = 0; mf < MF; ++mf){
          int co = wid * (MF * 16) + mf * 16 + l15;
          a[mf] = *(const bf16x8*)(Wp + ((size_t)(dir * COp + co) * CIT + cp * CIL + kb));
        }
        #pragma unroll
        for (int nf = 0; nf < 2; ++nf){
          int j = nf * 16 + l15 + dx;
          bf16x8 bfrag = *(const bf16x8*)(Xl + ((dy * 34 + j) * CIL + (kb ^ ((j & SWZ) << 3))));
          #pragma unroll
          for (int mf = 0; mf < MF; ++mf)
            acc[mf][nf] = __builtin_amdgcn_mfma_f32_16x16x32_bf16(a[mf], bfrag, acc[mf][nf], 0, 0, 0);
        }
      }
    }
  }
  #pragma unroll
  for (int mf = 0; mf < MF; ++mf){
    #pragma unroll
    for (int r = 0; r < 4; ++r){
      int co = wid * (MF * 16) + mf * 16 + q * 4 + r;
      if (CO != COp && co >= CO) continue;
      float bv = bias[co];
      float sv = 0.f, sq = 0.f;
      #pragma unroll
      for (int nf = 0; nf < 2; ++nf){
        int pix = nf * 16 + l15;
        float val = acc[mf][nf][r] + bv;
        out[(size_t)(b * CO + co) * 2048 + h * 64 + p0 + pix] = val;
        sv += val; sq += val * val;
      }
      #pragma unroll
      for (int off = 8; off; off >>= 1){
        sv += __shfl_xor(sv, off, 16);
        sq += __shfl_xor(sq, off, 16);
      }
      if (l15 == 0){
        bnp[((size_t)co * 512 + bh) * 2]     = sv;
        bnp[((size_t)co * 512 + bh) * 2 + 1] = sq;
      }
    }
  }
}

// ================= prep: BN1 finalize (redundant) + field prep, 6-way split =================
__global__ void __launch_bounds__(256) prep_k(const float* __restrict__ hb,
  const float* __restrict__ bnp1, GB gb,
  float* __restrict__ Fz, float* __restrict__ Fq, float* __restrict__ Fu,
  float* __restrict__ Fvf, float* __restrict__ Ft,
  float* __restrict__ zx, float* __restrict__ zy, float* __restrict__ zz,
  float* __restrict__ ux, float* __restrict__ vy, float* __restrict__ wv,
  float* __restrict__ partS)
{
  __shared__ float As[65], Bs[65];
  int blk = blockIdx.x, t = threadIdx.x;
  {
    int wvid = t >> 6, lane = t & 63;
    for (int ch = wvid; ch < 65; ch += 4){
      const float4* pp = (const float4*)(bnp1 + (size_t)ch * 1024) + lane * 4;
      float s = 0.f, sq = 0.f;
      #pragma unroll
      for (int k = 0; k < 4; ++k){ float4 v = pp[k]; s += v.x + v.z; sq += v.y + v.w; }
      s = waveRedSum(s); sq = waveRedSum(sq);
      if (!lane){
        float m = s * (1.f / 16384.f);
        float var = sq * (1.f / 16384.f) - m * m;
        float rstd = rsqrtf(var + 1e-5f);
        int f = ch / 13, k = ch - f * 13;
        float g = gb.g[f][k], bbv = gb.b[f][k];
        As[ch] = g * rstd; Bs[ch] = bbv - m * g * rstd;
      }
    }
  }
  __syncthreads();

  int part = blk >> 6;
  int col = ((blk & 63) << 8) | t;
  int b = col >> 11, p = col & 2047, h = p >> 6, w = p & 63;
  int hbase = b * 65 * NPLANE;
  auto hn = [&](int ch, int hh, int ww)->float {
    return hb[hbase + ch * 2048 + hh * 64 + ww] * As[ch] + Bs[ch];
  };
  int fb = (b * 13) * 2048 + p;
  float lat = latOf(h);
  float invpx = 1.0f / (PXCc * cosf(lat));
  int wm2 = (w + 62) & 63, wm1 = (w + 63) & 63, wpl1 = (w + 1) & 63, wpl2 = (w + 2) & 63;
  int hm2 = pmh(h - 2), hm1 = pmh(h - 1), hp1 = pmh(h + 1), hp2 = pmh(h + 2);
  float fmn = FBIG, fmx = -FBIG, fsm = 0.f, smn = FBIG, smx = -FBIG;
  if (part < 5){
    int ch0 = part * 13;
    float c[13];
    #pragma unroll
    for (int v = 0; v < 13; ++v) c[v] = hn(ch0 + v, h, w);
    float* Fdst = part == 0 ? Fz : part == 1 ? Fq : part == 2 ? Fu : part == 3 ? Fvf : Ft;
    #pragma unroll
    for (int v = 0; v < 13; ++v) Fdst[fb + v * 2048] = c[v];
    if (part == 0){
      #pragma unroll
      for (int v = 0; v < 13; ++v){
        zz[fb + v * 2048] = (-c[pmv(v - 2)] + 8.f * c[pmv(v - 1)] - 8.f * c[pmv(v + 1)] + c[pmv(v + 2)]) * cZI[v];
        float zxv = (hn(v, h, wm2) - 8.f * hn(v, h, wm1) + 8.f * hn(v, h, wpl1) - hn(v, h, wpl2)) * (1.f / 12.f) * invpx;
        float zyv = (-hn(v, hm2, w) + 8.f * hn(v, hm1, w) - 8.f * hn(v, hp1, w) + hn(v, hp2, w)) * (1.f / 12.f) * (1.f / PYc);
        zx[fb + v * 2048] = zxv; zy[fb + v * 2048] = zyv;
      }
    }
    if (part == 2){
      #pragma unroll
      for (int v = 0; v < 13; ++v){
        float uxv = (hn(26 + v, h, wm2) - 8.f * hn(26 + v, h, wm1) + 8.f * hn(26 + v, h, wpl1) - hn(26 + v, h, wpl2)) * (1.f / 12.f) * invpx;
        ux[fb + v * 2048] = uxv;
      }
    }
    if (part == 3){
      #pragma unroll
      for (int v = 0; v < 13; ++v){
        float vyv = (-hn(39 + v, hm2, w) + 8.f * hn(39 + v, hm1, w) - 8.f * hn(39 + v, hp1, w) + hn(39 + v, hp2, w)) * (1.f / 12.f) * (1.f / PYc);
        vy[fb + v * 2048] = vyv;
      }
    }
    if (part == 4){
      #pragma unroll
      for (int v = 0; v < 13; ++v){
        float tcc = c[v] - 273.15f;
        float arg = 17.67f * tcc / avoid_inf(tcc + 243.5f);
        smn = fminf(smn, arg); smx = fmaxf(smx, arg);
      }
    }
    #pragma unroll
    for (int v = 0; v < 13; ++v){ fmn = fminf(fmn, c[v]); fmx = fmaxf(fmx, c[v]); fsm += c[v]; }
  } else {
    float cum = 0.f;
    #pragma unroll
    for (int v = 0; v < 13; ++v){
      float uxv = (hn(26 + v, h, wm2) - 8.f * hn(26 + v, h, wm1) + 8.f * hn(26 + v, h, wpl1) - hn(26 + v, h, wpl2)) * (1.f / 12.f) * invpx;
      float vyv = (-hn(39 + v, hm2, w) + 8.f * hn(39 + v, hm1, w) - 8.f * hn(39 + v, hp1, w) + hn(39 + v, hp2, w)) * (1.f / 12.f) * (1.f / PYc);
      cum += cDZ[v] * (uxv + vyv);
      wv[fb + v * 2048] = -cum;
    }
  }
  float* pb = partS + blk * 17;
  float r;
  r = blockRedN<1,4>(smn); if (!t) pb[0] = r;
  r = blockRedN<2,4>(smx); if (!t) pb[1] = r;
  #pragma unroll
  for (int f = 0; f < 5; ++f){
    r = blockRedN<1,4>(part == f ? fmn : FBIG);  if (!t) pb[2 + f * 3] = r;
    r = blockRedN<2,4>(part == f ? fmx : -FBIG); if (!t) pb[3 + f * 3] = r;
    r = blockRedN<0,4>(part == f ? fsm : 0.f);   if (!t) pb[4 + f * 3] = r;
  }
}

// ===== monolithic RK stage; block = (b,h) column: 832 threads = 13 v x 64 w =====
// Stage 4 folds the z-tendency integral (LDS prefix over v) — no zt launch, no k4t buffer.
template<int STAGE>
__global__ void __launch_bounds__(832) stage_k(
  const float* __restrict__ U, const float* __restrict__ Vf, const float* __restrict__ T,
  const float* __restrict__ Fu, const float* __restrict__ Fvf, const float* __restrict__ Ft,
  const float* __restrict__ Fq,
  const float* __restrict__ ux, const float* __restrict__ vy,
  const float* __restrict__ zx, const float* __restrict__ zy,
  const float* __restrict__ wv, const float* __restrict__ zz,
  const float* __restrict__ partS,
  float* C0, float* prr,
  float* Uo, float* Vo, float* To,
  float* duA, float* dvA, float* dtA, float* qtA, float* ztA,
  float* pduv, float* pdt, float* pqt, float* pzt, float cnext)
{
  __shared__ float Zk[13 * 64];
  int blk = blockIdx.x, t = threadIdx.x;

  float ss = 0.f, off = 0.f;
  if (STAGE == 1){
    float v0 = (t < 384) ? partS[t * 17] : FBIG;
    float v1 = (t < 384) ? partS[t * 17 + 1] : -FBIG;
    float smn = blockRedN<1,13>(v0);
    float smx = blockRedN<2,13>(v1);
    ss = (3.01f + 3.47f) / (smx - smn);
    off = -3.47f - smn * ss;
  }

  int b = blk >> 5, h = blk & 31;
  int v = t >> 6, w = t & 63;
  int bv = b * 13 + v;
  int bvbase = bv * 2048;
  int rb = bvbase + h * 64;
  int bbase = (b * 13) * 2048;
  int hw = h * 64 + w;
  int i = bvbase + hw;
  float lat = latOf(h);
  float invpx = 1.0f / (PXCc * cosf(lat));
  float fcor = 2.0f * OMEGAc * sinf(lat);
  float wvi = wv[i];
  float Ui = U[i], Vi = Vf[i], Ti = T[i];
  float Fui = (STAGE == 1) ? Ui : Fu[i];
  float Fvi = (STAGE == 1) ? Vi : Fvf[i];

  // ---- u,v tendencies ----
  float dyU = d_yf(U, bvbase, h, w);
  float dzU = d_zf(U, bbase, v, hw);
  float dxV = d_xf(Vf, rb, w, invpx);
  float dzV = d_zf(Vf, bbase, v, hw);
  float mixU = KHc * (dxxf(U, rb, w, invpx) + dyyf(U, bvbase, h, w)) + KVc * dzzf(U, bbase, v, hw);
  float mixV = KHc * (dxxf(Vf, rb, w, invpx) + dyyf(Vf, bvbase, h, w)) + KVc * dzzf(Vf, bbase, v, hw);
  float ku = -Ui * ux[i] - Vi * dyU - wvi * dzU + fcor * Vi - zx[i] + mixU;
  float kv = -Ui * dxV - Vi * vy[i] - wvi * dzV - fcor * Ui - zy[i] + mixV;

  // ---- C0 ----
  float C0i;
  if (STAGE == 1){
    float zzi = zz[i], qi = Fq[i];
    float rho = -1.0f / avoid_inf(zzi);
    float p = rho * R_GASc * Ti;
    float tcc = Ti - 273.15f;
    float arg = 17.67f * tcc / avoid_inf(tcc + 243.5f);
    float es = 6.112f * expf(arg * ss + off) * 100.0f;
    float qs = fmaxf(0.622f * es / avoid_inf(p - 0.378f * es), 1e-6f);
    float rh = qi / avoid_inf(qs);
    float rate = (rh > PTHc) ? (qi - PTHc * qs) * (1.0f / DT) : 0.0f;
    prr[i] = rate;
    C0i = -(L_Vc + 1.0f) * zzi * wvi * (1.0f / C_Pc) + rate * (L_Vc / C_Pc);
    C0[i] = C0i;
  } else {
    C0i = C0[i];
  }

  // ---- t tendency ----
  float dxT = d_xf(T, rb, w, invpx);
  float dyT = d_yf(T, bvbase, h, w);
  float dzT = d_zf(T, bbase, v, hw);
  float mixT = KHc * (dxxf(T, rb, w, invpx) + dyyf(T, bvbase, h, w)) + KVc * dzzf(T, bbase, v, hw);
  float ta = Ti + 273.15f;
  float t2 = ta * ta;
  float ta5 = t2 * t2 * ta;
  float rc = cRC[v] * ta5;
  float kt = C0i - Fui * dxT - Fvi * dyT - wvi * dzT + mixT + rc;

  // ---- accumulate / outputs ----
  if (STAGE == 1){ duA[i] = ku; dvA[i] = kv; dtA[i] = kt; }
  else if (STAGE < 4){ duA[i] += 2.f * ku; dvA[i] += 2.f * kv; dtA[i] += 2.f * kt; }
  else {
    float au = duA[i] + ku, av = dvA[i] + kv, at = dtA[i] + kt;
    duA[i] = au; dvA[i] = av; dtA[i] = at;
    Zk[v * 64 + w] = cZW[v] * kt;
    float m0 = blockRedN<1,13>(au), m1 = blockRedN<2,13>(au);
    float m2 = blockRedN<1,13>(av), m3 = blockRedN<2,13>(av);
    float m4 = blockRedN<1,13>(at), m5 = blockRedN<2,13>(at);
    if (!t){
      float* pp = pduv + blk * 4;
      pp[0] = m0; pp[1] = m1; pp[2] = m2; pp[3] = m3;
      pdt[blk * 2] = m4; pdt[blk * 2 + 1] = m5;
    }
    // z-integral over this column block (wave 0 handles the 64 w columns)
    if (t < 64){
      float cum = 0.f, mn = FBIG, mx = -FBIG;
      #pragma unroll
      for (int j = 0; j < 13; ++j){
        cum += Zk[j * 64 + t];
        ztA[bbase + j * 2048 + h * 64 + t] = cum;
        mn = fminf(mn, cum); mx = fmaxf(mx, cum);
      }
      mn = waveRedMin(mn); mx = waveRedMax(mx);
      if (!t){ pzt[blk * 2] = mn; pzt[blk * 2 + 1] = mx; }
    }
  }
  if (STAGE < 4){
    float Fti = (STAGE == 1) ? Ti : Ft[i];
    Uo[i] = Fui + cnext * ku;
    Vo[i] = Fvi + cnext * kv;
    To[i] = Fti + cnext * kt;
  }

  // ---- q tendency (once, at stage 2) ----
  if (STAGE == 2){
    float qtv = -Fui * d_xf(Fq, rb, w, invpx) - Fvi * d_yf(Fq, bvbase, h, w) - wvi * d_zf(Fq, bbase, v, hw)
              + KHc * (dxxf(Fq, rb, w, invpx) + dyyf(Fq, bvbase, h, w)) + KVc * dzzf(Fq, bbase, v, hw) - prr[i];
    qtA[i] = qtv;
    float m0 = blockRedN<1,13>(qtv), m1 = blockRedN<2,13>(qtv);
    if (!t){ pqt[blk * 2] = m0; pqt[blk * 2 + 1] = m1; }
  }
}

// ===== fused: redundant sc2 finalize + outmid (LDS tile) + bf16 transpose out =====
__global__ void __launch_bounds__(256) outmid_fused_k(
  const float* __restrict__ hb,
  const float* __restrict__ Fz, const float* __restrict__ Fq, const float* __restrict__ Fu,
  const float* __restrict__ Fvf, const float* __restrict__ Ft,
  const float* __restrict__ ztA, const float* __restrict__ qtA,
  const float* __restrict__ duA, const float* __restrict__ dvA, const float* __restrict__ dtA,
  const float* __restrict__ coef, const float* __restrict__ partS,
  const float* __restrict__ pduv, const float* __restrict__ pdt,
  const float* __restrict__ pqt, const float* __restrict__ pzt,
  unsigned short* __restrict__ MT)
{
  __shared__ float tileBig[65 * 66];
  int blk = blockIdx.x, t = threadIdx.x;

  float fmn[5] = {FBIG, FBIG, FBIG, FBIG, FBIG};
  float fmx[5] = {-FBIG, -FBIG, -FBIG, -FBIG, -FBIG};
  float fsm[5] = {0.f, 0.f, 0.f, 0.f, 0.f};
  #pragma unroll 1
  for (int r0 = t; r0 < 384; r0 += 256){
    const float* pr = partS + r0 * 17;
    #pragma unroll
    for (int f = 0; f < 5; ++f){
      fmn[f] = fminf(fmn[f], pr[2 + f * 3]);
      fmx[f] = fmaxf(fmx[f], pr[3 + f * 3]);
      fsm[f] += pr[4 + f * 3];
    }
  }
  #pragma unroll
  for (int f = 0; f < 5; ++f){
    fmn[f] = blockRedN<1,4>(fmn[f]);
    fmx[f] = blockRedN<2,4>(fmx[f]);
    fsm[f] = blockRedN<0,4>(fsm[f]);
  }
  // 256 partial rows, one per thread
  float dumn = pduv[t * 4],     dumx = pduv[t * 4 + 1];
  float dvmn = pduv[t * 4 + 2], dvmx = pduv[t * 4 + 3];
  float dtmn = pdt[t * 2],      dtmx = pdt[t * 2 + 1];
  float qmn = pqt[t * 2],       qmx = pqt[t * 2 + 1];
  float zmn = pzt[t * 2],       zmx = pzt[t * 2 + 1];
  dumn = blockRedN<1,4>(dumn); dumx = blockRedN<2,4>(dumx);
  dvmn = blockRedN<1,4>(dvmn); dvmx = blockRedN<2,4>(dvmx);
  dtmn = blockRedN<1,4>(dtmn); dtmx = blockRedN<2,4>(dtmx);
  qmn = blockRedN<1,4>(qmn);   qmx = blockRedN<2,4>(qmx);
  zmn = blockRedN<1,4>(zmn);   zmx = blockRedN<2,4>(zmx);

  float scf[5], off2[5];
  {
    float rmn[5] = {zmn, qmn, dumn, dvmn, dtmn};
    float rmx[5] = {zmx, qmx, dumx, dvmx, dtmx};
    float cfs[5] = {DT, DT, DT / 6.f, DT / 6.f, DT / 6.f};
    #pragma unroll
    for (int f = 0; f < 5; ++f){
      float mnf = fmn[f], mef = fsm[f] * (1.0f / (float)NF), mxf = fmx[f];
      float aa = (mnf - mef) * 0.05f, b2 = (mxf - mef) * 0.05f;
      float cf = cfs[f];
      float dmn = rmn[f] * cf, dmx = rmx[f] * cf;
      float s = (b2 - aa) / (dmx - dmn);
      scf[f] = s * cf; off2[f] = aa - dmn * s;
    }
  }

  int b = blk >> 5, h = blk & 31;
  #pragma unroll 1
  for (int idx = t; idx < 65 * 64; idx += 256){
    int c = idx >> 6, w = idx & 63;
    int f = c / 13, v = c - f * 13;
    int fi = (b * 13 + v) * 2048 + h * 64 + w;
    const float *Fp, *Rp;
    switch (f){
      case 0: Fp = Fz;  Rp = ztA; break;
      case 1: Fp = Fq;  Rp = qtA; break;
      case 2: Fp = Fu;  Rp = duA; break;
      case 3: Fp = Fvf; Rp = dvA; break;
      default: Fp = Ft; Rp = dtA; break;
    }
    float phys = Fp[fi] + Rp[fi] * scf[f] + off2[f];
    float cf = coef[c * 2048 + h * 64 + w];
    float hbv = hb[((size_t)(b * 65 + c)) * 2048 + h * 64 + w];
    tileBig[c * 66 + w] = cf * phys + (1.0f - cf) * hbv;
  }
  __syncthreads();
  #pragma unroll 1
  for (int ph = 0; ph < 6; ++ph){
    int cbase = ph * 16;
    int w = t >> 2, c4 = (t & 3) * 4;
    int c0 = cbase + c4;
    ushort4 o;
    o.x = (c0 + 0 < 65) ? f2bf(tileBig[(c0 + 0) * 66 + w]) : (unsigned short)0;
    o.y = (c0 + 1 < 65) ? f2bf(tileBig[(c0 + 1) * 66 + w]) : (unsigned short)0;
    o.z = (c0 + 2 < 65) ? f2bf(tileBig[(c0 + 2) * 66 + w]) : (unsigned short)0;
    o.w = (c0 + 3 < 65) ? f2bf(tileBig[(c0 + 3) * 66 + w]) : (unsigned short)0;
    *(ushort4*)(MT + (((size_t)(b * 32 + h) * 64 + w) * 96 + c0)) = o;
  }
}

// ===== final: redundant BN2 finalize + apply BN + residual =====
__global__ void __launch_bounds__(256) final_k(float* __restrict__ y, const float* __restrict__ x,
  const float* __restrict__ bnp2, const float* __restrict__ gblk, const float* __restrict__ bblk)
{
  int blk = blockIdx.x, t = threadIdx.x;
  int c = (blk >> 1) & 255;
  float4 pv = ((const float4*)(bnp2 + (size_t)c * 1024))[t];
  float s = pv.x + pv.z, sq = pv.y + pv.w;
  s = blockRedN<0,4>(s); sq = blockRedN<0,4>(sq);
  float m = s * (1.0f / 16384.0f);
  float var = sq * (1.0f / 16384.0f) - m * m;
  float rstd = rsqrtf(var + 1e-5f);
  float a = gblk[c] * rstd, bb = bblk[c] - m * gblk[c] * rstd;
  int e4 = blk * 256 + t;
  float4 v = ((const float4*)y)[e4];
  float4 xv = ((const float4*)x)[e4];
  v.x = v.x * a + bb + xv.x;
  v.y = v.y * a + bb + xv.y;
  v.z = v.z * a + bb + xv.z;
  v.w = v.w * a + bb + xv.w;
  ((float4*)y)[e4] = v;
}

extern "C" void kernel_launch(void* const* d_in, const int* in_sizes, int n_in,
                              void* d_out, int out_size, void* d_ws, size_t ws_size,
                              hipStream_t stream)
{
  (void)in_sizes; (void)n_in; (void)out_size; (void)ws_size;
  const float* x        = (const float*)d_in[0];
  const float* w_norm   = (const float*)d_in[1];
  const float* b_norm   = (const float*)d_in[2];
  const float* w_innorm = (const float*)d_in[3];
  const float* b_innorm = (const float*)d_in[4];
  const float* coef     = (const float*)d_in[5];
  GB gb;
  for (int f = 0; f < 5; ++f){
    gb.g[f] = (const float*)d_in[6 + 2 * f];
    gb.b[f] = (const float*)d_in[7 + 2 * f];
  }
  const float* gblk = (const float*)d_in[16];
  const float* bblk = (const float*)d_in[17];
  float* yout = (float*)d_out;

  float* ws = (float*)d_ws;
  size_t off = 0;
  auto alloc = [&](size_t n){ float* p = ws + off; off += n; return p; };
  float* hb  = alloc(NHB);
  float* Fz  = alloc(NF); float* Fq  = alloc(NF); float* Fu  = alloc(NF);
  float* Fvf = alloc(NF); float* Ft  = alloc(NF);
  float* zx  = alloc(NF); float* zy  = alloc(NF); float* zz  = alloc(NF);
  float* ux  = alloc(NF); float* vy  = alloc(NF); float* wvel = alloc(NF);
  float* C0  = alloc(NF); float* prr = alloc(NF);
  float* Ua  = alloc(NF); float* Ub  = alloc(NF); float* Va  = alloc(NF); float* Vb = alloc(NF);
  float* Ta  = alloc(NF); float* Tb  = alloc(NF);
  float* duA = alloc(NF); float* dvA = alloc(NF); float* dtA = alloc(NF);
  float* ztA = alloc(NF); float* qtA = alloc(NF);
  float* part1 = alloc(384 * 17 + 4);
  float* pduv = alloc(256 * 4); float* pdt = alloc(256 * 2);
  float* pqt  = alloc(256 * 2); float* pzt = alloc(256 * 2);
  float* bnp1 = alloc(65 * 512 * 2);
  float* bnp2 = alloc(256 * 512 * 2);
  float* Wp1f = alloc(9 * 80 * 256 / 2);
  float* Wp2f = alloc(9 * 256 * 96 / 2);
  unsigned short* Wp1 = (unsigned short*)Wp1f;
  unsigned short* Wp2 = (unsigned short*)Wp2f;
  // XT bf16 (8.39 MB) aliases Ua..qtA (11*NF*4 = 9.37 MB); dead after conv1,
  // before stage1 writes Ua.
  unsigned short* XT = (unsigned short*)Ua;
  // MT bf16 (3.15 MB) aliases C0,prr,Ua,Ub (3.4 MB) — all dead after stage4;
  // outmid reads none of them.
  unsigned short* MT = (unsigned short*)C0;

  // 1. transpose x + pack both weights
  pre_k<<<3632, 256, 0, stream>>>(x, w_norm, w_innorm, XT, Wp1, Wp2);
  // 2. conv1 (bf16 MFMA, BN1 partials in epilogue)
  conv_mfma_k<256, 128, 65, 80, 5, 1, 7><<<dim3(64, 8), 5 * 64, 0, stream>>>(XT, Wp1, b_norm, hb, bnp1);
  // 3. prep (redundant BN1 finalize + 6-way field split + stat partials)
  prep_k<<<384, 256, 0, stream>>>(hb, bnp1, gb, Fz, Fq, Fu, Fvf, Ft, zx, zy, zz, ux, vy, wvel, part1);
  // 4-7. RK stages: monolithic u+v+t per thread, (b,h)-column blocks (13 waves);
  //      stage 2 adds q-tendency, stage 4 folds the z-integral.
  stage_k<1><<<256, 832, 0, stream>>>(Fu, Fvf, Ft, Fu, Fvf, Ft, Fq, ux, vy, zx, zy, wvel, zz, part1,
      C0, prr, Ua, Va, Ta, duA, dvA, dtA, qtA, ztA, pduv, pdt, pqt, pzt, 0.5f * DT);
  stage_k<2><<<256, 832, 0, stream>>>(Ua, Va, Ta, Fu, Fvf, Ft, Fq, ux, vy, zx, zy, wvel, zz, part1,
      C0, prr, Ub, Vb, Tb, duA, dvA, dtA, qtA, ztA, pduv, pdt, pqt, pzt, 0.5f * DT);
  stage_k<3><<<256, 832, 0, stream>>>(Ub, Vb, Tb, Fu, Fvf, Ft, Fq, ux, vy, zx, zy, wvel, zz, part1,
      C0, prr, Ua, Va, Ta, duA, dvA, dtA, qtA, ztA, pduv, pdt, pqt, pzt, DT);
  stage_k<4><<<256, 832, 0, stream>>>(Ua, Va, Ta, Fu, Fvf, Ft, Fq, ux, vy, zx, zy, wvel, zz, part1,
      C0, prr, Ub, Vb, Tb, duA, dvA, dtA, qtA, ztA, pduv, pdt, pqt, pzt, 0.f);
  // 8. fused finalize + outmid + bf16 transpose
  outmid_fused_k<<<256, 256, 0, stream>>>(hb, Fz, Fq, Fu, Fvf, Ft, ztA, qtA, duA, dvA, dtA,
      coef, part1, pduv, pdt, pqt, pzt, MT);
  // 9. conv2 (BN2 partials in epilogue)
  conv_mfma_k<96, 96, 256, 256, 8, 2, 3><<<dim3(64, 8), 8 * 64, 0, stream>>>(MT, Wp2, b_innorm, yout, bnp2);
  // 10. redundant BN2 finalize + apply + residual
  final_k<<<4096, 256, 0, stream>>>(yout, x, bnp2, gblk, bblk);
}

// Round 12
// 177.744 us; speedup vs baseline: 1.1613x; 1.1613x over previous
//
#include <hip/hip_runtime.h>
#include <math.h>

#define DEVFN static __device__ __forceinline__

static constexpr int BB = 8, VV = 13, HH = 32, WW = 64;
static constexpr int NPLANE = HH * WW;        // 2048
static constexpr int NF = BB * VV * NPLANE;   // 212992
static constexpr int NHB = BB * 65 * NPLANE;  // 1064960

static constexpr float DT = 300.0f;
static constexpr float KHc = 15.0f, KVc = 0.1f;
static constexpr float OMEGAc = 7.29e-5f;
static constexpr float L_Vc = 2.5e6f;
static constexpr float R_GASc = 8.314f;
static constexpr float C_Pc = 1005.0f;
static constexpr float PTHc = 0.8f;
static constexpr float PYc  = (float)(3.14159265358979323846 * 6371000.0 / 33.0);
static constexpr float PXCc = (float)(2.0 * 3.14159265358979323846 * 6371000.0 / 64.0);
static constexpr double RCCd = 0.7 * 5.67e-8 * 287.0 / (1005.0 * 100.0);
static constexpr float FBIG = 3.402823466e38f;

__constant__ float cDZ[13]  = {50,50,50,50,50,75,100,100,100,125,112,75,75};
// (1/12)/dz
__constant__ float cZI[13] = {
  (float)(1.0/600.0), (float)(1.0/600.0), (float)(1.0/600.0), (float)(1.0/600.0), (float)(1.0/600.0),
  (float)(1.0/900.0), (float)(1.0/1200.0), (float)(1.0/1200.0), (float)(1.0/1200.0),
  (float)(1.0/1500.0), (float)(1.0/1344.0), (float)(1.0/900.0), (float)(1.0/900.0)};
// -RCC/pressure
__constant__ float cRC[13] = {
  (float)(-RCCd/50.0), (float)(-RCCd/100.0), (float)(-RCCd/150.0), (float)(-RCCd/200.0),
  (float)(-RCCd/250.0), (float)(-RCCd/300.0), (float)(-RCCd/400.0), (float)(-RCCd/500.0),
  (float)(-RCCd/600.0), (float)(-RCCd/700.0), (float)(-RCCd/850.0), (float)(-RCCd/925.0),
  (float)(-RCCd/1000.0)};
// dz * (-R_GAS/pressure)
__constant__ float cZW[13] = {
  (float)(50.0*(-8.314/50.0)), (float)(50.0*(-8.314/100.0)), (float)(50.0*(-8.314/150.0)),
  (float)(50.0*(-8.314/200.0)), (float)(50.0*(-8.314/250.0)), (float)(75.0*(-8.314/300.0)),
  (float)(100.0*(-8.314/400.0)), (float)(100.0*(-8.314/500.0)), (float)(100.0*(-8.314/600.0)),
  (float)(125.0*(-8.314/700.0)), (float)(112.0*(-8.314/850.0)), (float)(75.0*(-8.314/925.0)),
  (float)(75.0*(-8.314/1000.0))};

typedef short bf16x8 __attribute__((ext_vector_type(8)));
typedef float f32x4 __attribute__((ext_vector_type(4)));

DEVFN int pmh(int r){ return r < 0 ? r + 2 : (r > HH - 1 ? r - 2 : r); }
DEVFN int pmv(int r){ return r < 0 ? r + 2 : (r > VV - 1 ? r - 2 : r); }
DEVFN float latOf(int h){ return (90.0f - (float)(h + 1) * (180.0f / 33.0f)) * 0.017453292519943295f; }
DEVFN float avoid_inf(float t){
  if (t == 0.0f) t = 0.1f;
  if (fabsf(t) < 1.0f) t = copysignf(1.0f, t);
  return t;
}
DEVFN unsigned short f2bf(float f){
  unsigned u = __float_as_uint(f);
  unsigned r = (u + 0x7fffu + ((u >> 16) & 1u)) >> 16;
  return (unsigned short)r;
}

// ---- global-memory stencils on [B][13][32][64] ----
DEVFN float d_xf(const float* __restrict__ F, int rb, int w, float invpx){
  return (F[rb + ((w + 62) & 63)] - 8.f * F[rb + ((w + 63) & 63)]
        + 8.f * F[rb + ((w + 1) & 63)] - F[rb + ((w + 2) & 63)]) * (1.f / 12.f) * invpx;
}
DEVFN float d_yf(const float* __restrict__ F, int bvbase, int h, int w){
  return (-F[bvbase + pmh(h - 2) * 64 + w] + 8.f * F[bvbase + pmh(h - 1) * 64 + w]
          - 8.f * F[bvbase + pmh(h + 1) * 64 + w] + F[bvbase + pmh(h + 2) * 64 + w]) * (1.f / 12.f) * (1.f / PYc);
}
DEVFN float d_zf(const float* __restrict__ F, int bbase, int v, int hw){
  return (-F[bbase + pmv(v - 2) * 2048 + hw] + 8.f * F[bbase + pmv(v - 1) * 2048 + hw]
          - 8.f * F[bbase + pmv(v + 1) * 2048 + hw] + F[bbase + pmv(v + 2) * 2048 + hw]) * cZI[v];
}
DEVFN float dxxf(const float* __restrict__ F, int rb, int w, float invpx){
  float s = F[rb + ((w + 60) & 63)] - 16.f * F[rb + ((w + 61) & 63)] + 64.f * F[rb + ((w + 62) & 63)]
          + 16.f * F[rb + ((w + 63) & 63)] - 130.f * F[rb + w] + 16.f * F[rb + ((w + 1) & 63)]
          + 64.f * F[rb + ((w + 2) & 63)] - 16.f * F[rb + ((w + 3) & 63)] + F[rb + ((w + 4) & 63)];
  return s * (1.f / 144.f) * invpx * invpx;
}
DEVFN float dyyf(const float* __restrict__ F, int bvbase, int h, int w){
  float g0 = d_yf(F, bvbase, pmh(h - 2), w);
  float g1 = d_yf(F, bvbase, pmh(h - 1), w);
  float g2 = d_yf(F, bvbase, pmh(h + 1), w);
  float g3 = d_yf(F, bvbase, pmh(h + 2), w);
  return (-g0 + 8.f * g1 - 8.f * g2 + g3) * (1.f / 12.f) * (1.f / PYc);
}
DEVFN float dzzf(const float* __restrict__ F, int bbase, int v, int hw){
  float g0 = d_zf(F, bbase, pmv(v - 2), hw);
  float g1 = d_zf(F, bbase, pmv(v - 1), hw);
  float g2 = d_zf(F, bbase, pmv(v + 1), hw);
  float g3 = d_zf(F, bbase, pmv(v + 2), hw);
  return (-g0 + 8.f * g1 - 8.f * g2 + g3) * cZI[v];
}

// ---- reductions ----
DEVFN float waveRedSum(float v){ for (int o = 32; o; o >>= 1) v += __shfl_down(v, o, 64); return v; }
DEVFN float waveRedMin(float v){ for (int o = 32; o; o >>= 1) v = fminf(v, __shfl_down(v, o, 64)); return v; }
DEVFN float waveRedMax(float v){ for (int o = 32; o; o >>= 1) v = fmaxf(v, __shfl_down(v, o, 64)); return v; }

template<int OP, int NWV>
static __device__ float blockRedN(float v){
  __shared__ float s[NWV];
  v = OP == 0 ? waveRedSum(v) : OP == 1 ? waveRedMin(v) : waveRedMax(v);
  int lane = threadIdx.x & 63, wid = threadIdx.x >> 6;
  __syncthreads();
  if (lane == 0) s[wid] = v;
  __syncthreads();
  float r = s[0];
  #pragma unroll
  for (int k = 1; k < NWV; ++k)
    r = OP == 0 ? r + s[k] : OP == 1 ? fminf(r, s[k]) : fmaxf(r, s[k]);
  return r;
}

struct GB { const float* g[5]; const float* b[5]; };

// ================= launch 1: transpose x + pack both weights =================
__global__ void __launch_bounds__(256) pre_k(const float* __restrict__ x,
    const float* __restrict__ w1, const float* __restrict__ w2,
    unsigned short* __restrict__ XT, unsigned short* __restrict__ wp1,
    unsigned short* __restrict__ wp2)
{
  int blk = blockIdx.x, t = threadIdx.x;
  if (blk < 1024){
    __shared__ float tile[16 * 68];
    int zz = blk >> 8, rem = blk & 255;
    int b = rem >> 5, h = rem & 31;
    for (int p = zz * 4; p < zz * 4 + 4; ++p){
      int cbase = p * 16;
      __syncthreads();
      {
        int cl = t >> 4, w4 = (t & 15) * 4;
        float4 v = *(const float4*)(x + (((size_t)(b * 256 + cbase + cl) * 32 + h) * 64 + w4));
        tile[cl * 68 + w4 + 0] = v.x; tile[cl * 68 + w4 + 1] = v.y;
        tile[cl * 68 + w4 + 2] = v.z; tile[cl * 68 + w4 + 3] = v.w;
      }
      __syncthreads();
      {
        int w = t >> 2, c4 = (t & 3) * 4;
        ushort4 o;
        o.x = f2bf(tile[(c4 + 0) * 68 + w]);
        o.y = f2bf(tile[(c4 + 1) * 68 + w]);
        o.z = f2bf(tile[(c4 + 2) * 68 + w]);
        o.w = f2bf(tile[(c4 + 3) * 68 + w]);
        *(ushort4*)(XT + (((size_t)(b * 32 + h) * 64 + w) * 256 + cbase + c4)) = o;
      }
    }
  } else {
    const int T1 = 9 * 80 * 256;
    const int T2 = 9 * 256 * 96;
    int idx = (blk - 1024) * 256 + t;
    if (idx < T1){
      int dir = idx / (80 * 256);
      int r = idx - dir * (80 * 256);
      int co = r / 256, ci = r - co * 256;
      float v = (co < 65) ? w1[((size_t)(co * 256 + ci)) * 9 + dir] : 0.f;
      wp1[idx] = f2bf(v);
    } else if (idx < T1 + T2){
      int j = idx - T1;
      int dir = j / (256 * 96);
      int r = j - dir * (256 * 96);
      int co = r / 96, ci = r - co * 96;
      float v = (ci < 65) ? w2[((size_t)(co * 65 + ci)) * 9 + dir] : 0.f;
      wp2[j] = f2bf(v);
    }
  }
}

// ================= conv via MFMA; 32-pixel blocks; BN partials in epilogue =================
template<int CIT, int CIL, int CO, int COp, int NW, int MF, int SWZ>
__global__ void __launch_bounds__(NW * 64) conv_mfma_k(
    const unsigned short* __restrict__ XT, const unsigned short* __restrict__ Wp,
    const float* __restrict__ bias, float* __restrict__ out, float* __restrict__ bnp)
{
  __shared__ __align__(16) unsigned short Xl[3 * 34 * CIL];
  const int C8 = CIL / 8;
  int tid = threadIdx.x;
  int bx = blockIdx.x, b = blockIdx.y;
  int h = bx >> 1, p0 = (bx & 1) << 5;
  int bh = b * 64 + bx;
  int wid = tid >> 6, lane = tid & 63;
  int l15 = lane & 15, q = lane >> 4;

  f32x4 acc[MF][2];
  #pragma unroll
  for (int mf = 0; mf < MF; ++mf)
    #pragma unroll
    for (int nf = 0; nf < 2; ++nf){ f32x4 z = {0.f, 0.f, 0.f, 0.f}; acc[mf][nf] = z; }

  for (int cp = 0; cp < CIT / CIL; ++cp){
    if (cp) __syncthreads();
    for (int idx = tid; idx < 3 * 34 * C8; idx += NW * 64){
      int r = idx / (34 * C8);
      int rest = idx - r * (34 * C8);
      int j = rest / C8;
      int c8 = rest - j * C8;
      int hh = h + r - 1;
      int gw = p0 - 1 + j;
      uint4 val = make_uint4(0, 0, 0, 0);
      if (hh >= 0 && hh < 32 && gw >= 0 && gw < 64)
        val = *(const uint4*)(XT + (((size_t)(b * 32 + hh) * 64 + gw) * CIT + cp * CIL + c8 * 8));
      int dst = (r * 34 + j) * CIL + ((c8 * 8) ^ ((j & SWZ) << 3));
      *(uint4*)(Xl + dst) = val;
    }
    __syncthreads();

    for (int dir = 0; dir < 9; ++dir){
      int dy = dir / 3, dx = dir - dy * 3;
      #pragma unroll
      for (int kc = 0; kc < CIL / 32; ++kc){
        int kb = kc * 32 + q * 8;
        bf16x8 a[MF];
        #pragma unroll
        for (int mf = 0; mf < MF; ++mf){
          int co = wid * (MF * 16) + mf * 16 + l15;
          a[mf] = *(const bf16x8*)(Wp + ((size_t)(dir * COp + co) * CIT + cp * CIL + kb));
        }
        #pragma unroll
        for (int nf = 0; nf < 2; ++nf){
          int j = nf * 16 + l15 + dx;
          bf16x8 bfrag = *(const bf16x8*)(Xl + ((dy * 34 + j) * CIL + (kb ^ ((j & SWZ) << 3))));
          #pragma unroll
          for (int mf = 0; mf < MF; ++mf)
            acc[mf][nf] = __builtin_amdgcn_mfma_f32_16x16x32_bf16(a[mf], bfrag, acc[mf][nf], 0, 0, 0);
        }
      }
    }
  }
  #pragma unroll
  for (int mf = 0; mf < MF; ++mf){
    #pragma unroll
    for (int r = 0; r < 4; ++r){
      int co = wid * (MF * 16) + mf * 16 + q * 4 + r;
      if (CO != COp && co >= CO) continue;
      float bv = bias[co];
      float sv = 0.f, sq = 0.f;
      #pragma unroll
      for (int nf = 0; nf < 2; ++nf){
        int pix = nf * 16 + l15;
        float val = acc[mf][nf][r] + bv;
        out[(size_t)(b * CO + co) * 2048 + h * 64 + p0 + pix] = val;
        sv += val; sq += val * val;
      }
      #pragma unroll
      for (int off = 8; off; off >>= 1){
        sv += __shfl_xor(sv, off, 16);
        sq += __shfl_xor(sq, off, 16);
      }
      if (l15 == 0){
        bnp[((size_t)co * 512 + bh) * 2]     = sv;
        bnp[((size_t)co * 512 + bh) * 2 + 1] = sq;
      }
    }
  }
}

// ================= prep: BN1 finalize (redundant) + field prep, XCD-swizzled =================
__global__ void __launch_bounds__(256) prep_k(const float* __restrict__ hb,
  const float* __restrict__ bnp1, GB gb,
  float* __restrict__ Fz, float* __restrict__ Fq, float* __restrict__ Fu,
  float* __restrict__ Fvf, float* __restrict__ Ft,
  float* __restrict__ zx, float* __restrict__ zy, float* __restrict__ zz,
  float* __restrict__ ux, float* __restrict__ vy, float* __restrict__ wv,
  float* __restrict__ partS)
{
  __shared__ float As[65], Bs[65];
  int blk = blockIdx.x, t = threadIdx.x;
  {
    int wvid = t >> 6, lane = t & 63;
    for (int ch = wvid; ch < 65; ch += 4){
      const float4* pp = (const float4*)(bnp1 + (size_t)ch * 1024) + lane * 4;
      float s = 0.f, sq = 0.f;
      #pragma unroll
      for (int k = 0; k < 4; ++k){ float4 v = pp[k]; s += v.x + v.z; sq += v.y + v.w; }
      s = waveRedSum(s); sq = waveRedSum(sq);
      if (!lane){
        float m = s * (1.f / 16384.f);
        float var = sq * (1.f / 16384.f) - m * m;
        float rstd = rsqrtf(var + 1e-5f);
        int f = ch / 13, k = ch - f * 13;
        float g = gb.g[f][k], bbv = gb.b[f][k];
        As[ch] = g * rstd; Bs[ch] = bbv - m * g * rstd;
      }
    }
  }
  __syncthreads();

  int part = blk >> 6;
  int chunk = blk & 63;
  int b = chunk & 7;                       // XCD-aligned: blk%8 fixes batch
  int p = ((chunk >> 3) << 8) | t;         // 8 chunks x 256 = 2048 pixels
  int h = p >> 6, w = p & 63;
  int hbase = b * 65 * NPLANE;
  auto hn = [&](int ch, int hh, int ww)->float {
    return hb[hbase + ch * 2048 + hh * 64 + ww] * As[ch] + Bs[ch];
  };
  int fb = (b * 13) * 2048 + p;
  float lat = latOf(h);
  float invpx = 1.0f / (PXCc * cosf(lat));
  int wm2 = (w + 62) & 63, wm1 = (w + 63) & 63, wpl1 = (w + 1) & 63, wpl2 = (w + 2) & 63;
  int hm2 = pmh(h - 2), hm1 = pmh(h - 1), hp1 = pmh(h + 1), hp2 = pmh(h + 2);
  float fmn = FBIG, fmx = -FBIG, fsm = 0.f, smn = FBIG, smx = -FBIG;
  if (part < 5){
    int ch0 = part * 13;
    float c[13];
    #pragma unroll
    for (int v = 0; v < 13; ++v) c[v] = hn(ch0 + v, h, w);
    float* Fdst = part == 0 ? Fz : part == 1 ? Fq : part == 2 ? Fu : part == 3 ? Fvf : Ft;
    #pragma unroll
    for (int v = 0; v < 13; ++v) Fdst[fb + v * 2048] = c[v];
    if (part == 0){
      #pragma unroll
      for (int v = 0; v < 13; ++v){
        zz[fb + v * 2048] = (-c[pmv(v - 2)] + 8.f * c[pmv(v - 1)] - 8.f * c[pmv(v + 1)] + c[pmv(v + 2)]) * cZI[v];
        float zxv = (hn(v, h, wm2) - 8.f * hn(v, h, wm1) + 8.f * hn(v, h, wpl1) - hn(v, h, wpl2)) * (1.f / 12.f) * invpx;
        float zyv = (-hn(v, hm2, w) + 8.f * hn(v, hm1, w) - 8.f * hn(v, hp1, w) + hn(v, hp2, w)) * (1.f / 12.f) * (1.f / PYc);
        zx[fb + v * 2048] = zxv; zy[fb + v * 2048] = zyv;
      }
    }
    if (part == 2){
      #pragma unroll
      for (int v = 0; v < 13; ++v){
        float uxv = (hn(26 + v, h, wm2) - 8.f * hn(26 + v, h, wm1) + 8.f * hn(26 + v, h, wpl1) - hn(26 + v, h, wpl2)) * (1.f / 12.f) * invpx;
        ux[fb + v * 2048] = uxv;
      }
    }
    if (part == 3){
      #pragma unroll
      for (int v = 0; v < 13; ++v){
        float vyv = (-hn(39 + v, hm2, w) + 8.f * hn(39 + v, hm1, w) - 8.f * hn(39 + v, hp1, w) + hn(39 + v, hp2, w)) * (1.f / 12.f) * (1.f / PYc);
        vy[fb + v * 2048] = vyv;
      }
    }
    if (part == 4){
      #pragma unroll
      for (int v = 0; v < 13; ++v){
        float tcc = c[v] - 273.15f;
        float arg = 17.67f * tcc / avoid_inf(tcc + 243.5f);
        smn = fminf(smn, arg); smx = fmaxf(smx, arg);
      }
    }
    #pragma unroll
    for (int v = 0; v < 13; ++v){ fmn = fminf(fmn, c[v]); fmx = fmaxf(fmx, c[v]); fsm += c[v]; }
  } else {
    float cum = 0.f;
    #pragma unroll
    for (int v = 0; v < 13; ++v){
      float uxv = (hn(26 + v, h, wm2) - 8.f * hn(26 + v, h, wm1) + 8.f * hn(26 + v, h, wpl1) - hn(26 + v, h, wpl2)) * (1.f / 12.f) * invpx;
      float vyv = (-hn(39 + v, hm2, w) + 8.f * hn(39 + v, hm1, w) - 8.f * hn(39 + v, hp1, w) + hn(39 + v, hp2, w)) * (1.f / 12.f) * (1.f / PYc);
      cum += cDZ[v] * (uxv + vyv);
      wv[fb + v * 2048] = -cum;
    }
  }
  float* pb = partS + blk * 17;
  float r;
  r = blockRedN<1,4>(smn); if (!t) pb[0] = r;
  r = blockRedN<2,4>(smx); if (!t) pb[1] = r;
  #pragma unroll
  for (int f = 0; f < 5; ++f){
    r = blockRedN<1,4>(part == f ? fmn : FBIG);  if (!t) pb[2 + f * 3] = r;
    r = blockRedN<2,4>(part == f ? fmx : -FBIG); if (!t) pb[3 + f * 3] = r;
    r = blockRedN<0,4>(part == f ? fsm : 0.f);   if (!t) pb[4 + f * 3] = r;
  }
}

// ===== merged RK stage (monolithic u+v+t), XCD-aligned batch swizzle =====
// blk&7 = batch (one batch per XCD under round-robin dispatch); rest = (v, h-group).
template<int STAGE>
__global__ void __launch_bounds__(256) stage_k(
  const float* __restrict__ U, const float* __restrict__ Vf, const float* __restrict__ T,
  const float* __restrict__ Fu, const float* __restrict__ Fvf, const float* __restrict__ Ft,
  const float* __restrict__ Fq,
  const float* __restrict__ ux, const float* __restrict__ vy,
  const float* __restrict__ zx, const float* __restrict__ zy,
  const float* __restrict__ wv, const float* __restrict__ zz,
  const float* __restrict__ partS,
  float* C0, float* prr,
  float* Uo, float* Vo, float* To,
  float* duA, float* dvA, float* dtA, float* k4t, float* qtA,
  float* pduv, float* pdt, float* pqt, float cnext)
{
  float ss = 0.f, off = 0.f;
  if (STAGE == 1){
    int tt = threadIdx.x;
    float v0 = partS[tt * 17], v1 = partS[tt * 17 + 1];
    if (tt < 128){
      v0 = fminf(v0, partS[(tt + 256) * 17]);
      v1 = fmaxf(v1, partS[(tt + 256) * 17 + 1]);
    }
    float smn = blockRedN<1,4>(v0);
    float smx = blockRedN<2,4>(v1);
    ss = (3.01f + 3.47f) / (smx - smn);
    off = -3.47f - smn * ss;
  }
  int blk = blockIdx.x, t = threadIdx.x;
  int b = blk & 7;
  int rest = blk >> 3;          // 0..103
  int v = rest % 13;
  int hg = rest / 13;           // 0..7
  int h = (hg << 2) | (t >> 6);
  int w = t & 63;
  int bv = b * 13 + v;
  int bvbase = bv * 2048;
  int rb = bvbase + h * 64;
  int bbase = b * 13 * 2048;
  int hw = h * 64 + w;
  int i = bvbase + hw;
  float lat = latOf(h);
  float invpx = 1.0f / (PXCc * cosf(lat));
  float fcor = 2.0f * OMEGAc * sinf(lat);
  float wvi = wv[i];
  float Ui = U[i], Vi = Vf[i], Ti = T[i];
  float Fui = (STAGE == 1) ? Ui : Fu[i];
  float Fvi = (STAGE == 1) ? Vi : Fvf[i];

  float dyU = d_yf(U, bvbase, h, w);
  float dzU = d_zf(U, bbase, v, hw);
  float dxV = d_xf(Vf, rb, w, invpx);
  float dzV = d_zf(Vf, bbase, v, hw);
  float mixU = KHc * (dxxf(U, rb, w, invpx) + dyyf(U, bvbase, h, w)) + KVc * dzzf(U, bbase, v, hw);
  float mixV = KHc * (dxxf(Vf, rb, w, invpx) + dyyf(Vf, bvbase, h, w)) + KVc * dzzf(Vf, bbase, v, hw);
  float ku = -Ui * ux[i] - Vi * dyU - wvi * dzU + fcor * Vi - zx[i] + mixU;
  float kv = -Ui * dxV - Vi * vy[i] - wvi * dzV - fcor * Ui - zy[i] + mixV;

  float C0i;
  if (STAGE == 1){
    float zzi = zz[i], qi = Fq[i];
    float rho = -1.0f / avoid_inf(zzi);
    float p = rho * R_GASc * Ti;               // Ti == Ft at stage 1
    float tcc = Ti - 273.15f;
    float arg = 17.67f * tcc / avoid_inf(tcc + 243.5f);
    float es = 6.112f * expf(arg * ss + off) * 100.0f;
    float qs = fmaxf(0.622f * es / avoid_inf(p - 0.378f * es), 1e-6f);
    float rh = qi / avoid_inf(qs);
    float rate = (rh > PTHc) ? (qi - PTHc * qs) * (1.0f / DT) : 0.0f;
    prr[i] = rate;
    C0i = -(L_Vc + 1.0f) * zzi * wvi * (1.0f / C_Pc) + rate * (L_Vc / C_Pc);
    C0[i] = C0i;
  } else {
    C0i = C0[i];
  }

  float dxT = d_xf(T, rb, w, invpx);
  float dyT = d_yf(T, bvbase, h, w);
  float dzT = d_zf(T, bbase, v, hw);
  float mixT = KHc * (dxxf(T, rb, w, invpx) + dyyf(T, bvbase, h, w)) + KVc * dzzf(T, bbase, v, hw);
  float ta = Ti + 273.15f;
  float t2 = ta * ta;
  float ta5 = t2 * t2 * ta;
  float rc = cRC[v] * ta5;
  float kt = C0i - Fui * dxT - Fvi * dyT - wvi * dzT + mixT + rc;

  if (STAGE == 1){ duA[i] = ku; dvA[i] = kv; dtA[i] = kt; }
  else if (STAGE < 4){ duA[i] += 2.f * ku; dvA[i] += 2.f * kv; dtA[i] += 2.f * kt; }
  else {
    float au = duA[i] + ku, av = dvA[i] + kv, at = dtA[i] + kt;
    duA[i] = au; dvA[i] = av; dtA[i] = at; k4t[i] = kt;
    float m0 = blockRedN<1,4>(au), m1 = blockRedN<2,4>(au);
    float m2 = blockRedN<1,4>(av), m3 = blockRedN<2,4>(av);
    float m4 = blockRedN<1,4>(at), m5 = blockRedN<2,4>(at);
    if (!t){
      float* pp = pduv + blk * 4;
      pp[0] = m0; pp[1] = m1; pp[2] = m2; pp[3] = m3;
      pdt[blk * 2] = m4; pdt[blk * 2 + 1] = m5;
    }
  }
  if (STAGE < 4){
    float Fti = (STAGE == 1) ? Ti : Ft[i];
    Uo[i] = Fui + cnext * ku;
    Vo[i] = Fvi + cnext * kv;
    To[i] = Fti + cnext * kt;
  }

  if (STAGE == 2){
    float qtv = -Fui * d_xf(Fq, rb, w, invpx) - Fvi * d_yf(Fq, bvbase, h, w) - wvi * d_zf(Fq, bbase, v, hw)
              + KHc * (dxxf(Fq, rb, w, invpx) + dyyf(Fq, bvbase, h, w)) + KVc * dzzf(Fq, bbase, v, hw) - prr[i];
    qtA[i] = qtv;
    float m0 = blockRedN<1,4>(qtv), m1 = blockRedN<2,4>(qtv);
    if (!t){ pqt[blk * 2] = m0; pqt[blk * 2 + 1] = m1; }
  }
}

__global__ void __launch_bounds__(64) zt_k(const float* __restrict__ k4t, float* __restrict__ zt, float* __restrict__ pmm)
{
  int blk = blockIdx.x;
  int b = blk & 7;                        // XCD-aligned batch
  int p = ((blk >> 3) << 6) + threadIdx.x;
  int fb = b * 13 * 2048 + p;
  float cum = 0.f, mn = FBIG, mx = -FBIG;
  #pragma unroll
  for (int v = 0; v < 13; ++v){
    cum += cZW[v] * k4t[fb + v * 2048];
    zt[fb + v * 2048] = cum;
    mn = fminf(mn, cum); mx = fmaxf(mx, cum);
  }
  mn = waveRedMin(mn); mx = waveRedMax(mx);
  if (!threadIdx.x){ pmm[blk * 2] = mn; pmm[blk * 2 + 1] = mx; }
}

// ===== fused: redundant sc2 finalize + outmid (LDS tile) + bf16 transpose out =====
__global__ void __launch_bounds__(256) outmid_fused_k(
  const float* __restrict__ hb,
  const float* __restrict__ Fz, const float* __restrict__ Fq, const float* __restrict__ Fu,
  const float* __restrict__ Fvf, const float* __restrict__ Ft,
  const float* __restrict__ ztA, const float* __restrict__ qtA,
  const float* __restrict__ duA, const float* __restrict__ dvA, const float* __restrict__ dtA,
  const float* __restrict__ coef, const float* __restrict__ partS,
  const float* __restrict__ pduv, const float* __restrict__ pdt,
  const float* __restrict__ pqt, const float* __restrict__ pzt,
  unsigned short* __restrict__ MT)
{
  __shared__ float tileBig[65 * 66];
  int blk = blockIdx.x, t = threadIdx.x;

  float fmn[5] = {FBIG, FBIG, FBIG, FBIG, FBIG};
  float fmx[5] = {-FBIG, -FBIG, -FBIG, -FBIG, -FBIG};
  float fsm[5] = {0.f, 0.f, 0.f, 0.f, 0.f};
  #pragma unroll 1
  for (int r0 = t; r0 < 384; r0 += 256){
    const float* pr = partS + r0 * 17;
    #pragma unroll
    for (int f = 0; f < 5; ++f){
      fmn[f] = fminf(fmn[f], pr[2 + f * 3]);
      fmx[f] = fmaxf(fmx[f], pr[3 + f * 3]);
      fsm[f] += pr[4 + f * 3];
    }
  }
  #pragma unroll
  for (int f = 0; f < 5; ++f){
    fmn[f] = blockRedN<1,4>(fmn[f]);
    fmx[f] = blockRedN<2,4>(fmx[f]);
    fsm[f] = blockRedN<0,4>(fsm[f]);
  }
  float dumn = FBIG, dumx = -FBIG, dvmn = FBIG, dvmx = -FBIG, dtmn = FBIG, dtmx = -FBIG;
  float qmn = FBIG, qmx = -FBIG;
  #pragma unroll 1
  for (int r0 = t; r0 < 832; r0 += 256){
    dumn = fminf(dumn, pduv[r0 * 4]);     dumx = fmaxf(dumx, pduv[r0 * 4 + 1]);
    dvmn = fminf(dvmn, pduv[r0 * 4 + 2]); dvmx = fmaxf(dvmx, pduv[r0 * 4 + 3]);
    dtmn = fminf(dtmn, pdt[r0 * 2]);      dtmx = fmaxf(dtmx, pdt[r0 * 2 + 1]);
    qmn = fminf(qmn, pqt[r0 * 2]);        qmx = fmaxf(qmx, pqt[r0 * 2 + 1]);
  }
  float zmn = pzt[t * 2], zmx = pzt[t * 2 + 1];
  dumn = blockRedN<1,4>(dumn); dumx = blockRedN<2,4>(dumx);
  dvmn = blockRedN<1,4>(dvmn); dvmx = blockRedN<2,4>(dvmx);
  dtmn = blockRedN<1,4>(dtmn); dtmx = blockRedN<2,4>(dtmx);
  qmn = blockRedN<1,4>(qmn);   qmx = blockRedN<2,4>(qmx);
  zmn = blockRedN<1,4>(zmn);   zmx = blockRedN<2,4>(zmx);

  float scf[5], off2[5];
  {
    float rmn[5] = {zmn, qmn, dumn, dvmn, dtmn};
    float rmx[5] = {zmx, qmx, dumx, dvmx, dtmx};
    float cfs[5] = {DT, DT, DT / 6.f, DT / 6.f, DT / 6.f};
    #pragma unroll
    for (int f = 0; f < 5; ++f){
      float mnf = fmn[f], mef = fsm[f] * (1.0f / (float)NF), mxf = fmx[f];
      float aa = (mnf - mef) * 0.05f, b2 = (mxf - mef) * 0.05f;
      float cf = cfs[f];
      float dmn = rmn[f] * cf, dmx = rmx[f] * cf;
      float s = (b2 - aa) / (dmx - dmn);
      scf[f] = s * cf; off2[f] = aa - dmn * s;
    }
  }

  int b = blk & 7, h = blk >> 3;          // XCD-aligned batch
  #pragma unroll 1
  for (int idx = t; idx < 65 * 64; idx += 256){
    int c = idx >> 6, w = idx & 63;
    int f = c / 13, v = c - f * 13;
    int fi = (b * 13 + v) * 2048 + h * 64 + w;
    const float *Fp, *Rp;
    switch (f){
      case 0: Fp = Fz;  Rp = ztA; break;
      case 1: Fp = Fq;  Rp = qtA; break;
      case 2: Fp = Fu;  Rp = duA; break;
      case 3: Fp = Fvf; Rp = dvA; break;
      default: Fp = Ft; Rp = dtA; break;
    }
    float phys = Fp[fi] + Rp[fi] * scf[f] + off2[f];
    float cf = coef[c * 2048 + h * 64 + w];
    float hbv = hb[((size_t)(b * 65 + c)) * 2048 + h * 64 + w];
    tileBig[c * 66 + w] = cf * phys + (1.0f - cf) * hbv;
  }
  __syncthreads();
  #pragma unroll 1
  for (int ph = 0; ph < 6; ++ph){
    int cbase = ph * 16;
    int w = t >> 2, c4 = (t & 3) * 4;
    int c0 = cbase + c4;
    ushort4 o;
    o.x = (c0 + 0 < 65) ? f2bf(tileBig[(c0 + 0) * 66 + w]) : (unsigned short)0;
    o.y = (c0 + 1 < 65) ? f2bf(tileBig[(c0 + 1) * 66 + w]) : (unsigned short)0;
    o.z = (c0 + 2 < 65) ? f2bf(tileBig[(c0 + 2) * 66 + w]) : (unsigned short)0;
    o.w = (c0 + 3 < 65) ? f2bf(tileBig[(c0 + 3) * 66 + w]) : (unsigned short)0;
    *(ushort4*)(MT + (((size_t)(b * 32 + h) * 64 + w) * 96 + c0)) = o;
  }
}

// ===== final: redundant BN2 finalize + apply BN + residual =====
__global__ void __launch_bounds__(256) final_k(float* __restrict__ y, const float* __restrict__ x,
  const float* __restrict__ bnp2, const float* __restrict__ gblk, const float* __restrict__ bblk)
{
  int blk = blockIdx.x, t = threadIdx.x;
  int c = (blk >> 1) & 255;
  float4 pv = ((const float4*)(bnp2 + (size_t)c * 1024))[t];
  float s = pv.x + pv.z, sq = pv.y + pv.w;
  s = blockRedN<0,4>(s); sq = blockRedN<0,4>(sq);
  float m = s * (1.0f / 16384.0f);
  float var = sq * (1.0f / 16384.0f) - m * m;
  float rstd = rsqrtf(var + 1e-5f);
  float a = gblk[c] * rstd, bb = bblk[c] - m * gblk[c] * rstd;
  int e4 = blk * 256 + t;
  float4 v = ((const float4*)y)[e4];
  float4 xv = ((const float4*)x)[e4];
  v.x = v.x * a + bb + xv.x;
  v.y = v.y * a + bb + xv.y;
  v.z = v.z * a + bb + xv.z;
  v.w = v.w * a + bb + xv.w;
  ((float4*)y)[e4] = v;
}

extern "C" void kernel_launch(void* const* d_in, const int* in_sizes, int n_in,
                              void* d_out, int out_size, void* d_ws, size_t ws_size,
                              hipStream_t stream)
{
  (void)in_sizes; (void)n_in; (void)out_size; (void)ws_size;
  const float* x        = (const float*)d_in[0];
  const float* w_norm   = (const float*)d_in[1];
  const float* b_norm   = (const float*)d_in[2];
  const float* w_innorm = (const float*)d_in[3];
  const float* b_innorm = (const float*)d_in[4];
  const float* coef     = (const float*)d_in[5];
  GB gb;
  for (int f = 0; f < 5; ++f){
    gb.g[f] = (const float*)d_in[6 + 2 * f];
    gb.b[f] = (const float*)d_in[7 + 2 * f];
  }
  const float* gblk = (const float*)d_in[16];
  const float* bblk = (const float*)d_in[17];
  float* yout = (float*)d_out;

  float* ws = (float*)d_ws;
  size_t off = 0;
  auto alloc = [&](size_t n){ float* p = ws + off; off += n; return p; };
  float* hb  = alloc(NHB);
  float* Fz  = alloc(NF); float* Fq  = alloc(NF); float* Fu  = alloc(NF);
  float* Fvf = alloc(NF); float* Ft  = alloc(NF);
  float* zx  = alloc(NF); float* zy  = alloc(NF); float* zz  = alloc(NF);
  float* ux  = alloc(NF); float* vy  = alloc(NF); float* wvel = alloc(NF);
  float* C0  = alloc(NF); float* prr = alloc(NF);
  float* Ua  = alloc(NF); float* Ub  = alloc(NF); float* Va  = alloc(NF); float* Vb = alloc(NF);
  float* Ta  = alloc(NF); float* Tb  = alloc(NF);
  float* duA = alloc(NF); float* dvA = alloc(NF); float* dtA = alloc(NF);
  float* k4t = alloc(NF); float* ztA = alloc(NF); float* qtA = alloc(NF);
  float* part1 = alloc(384 * 17 + 4);
  float* pduv = alloc(832 * 4); float* pdt = alloc(832 * 2);
  float* pqt  = alloc(832 * 2); float* pzt = alloc(256 * 2);
  float* bnp1 = alloc(65 * 512 * 2);
  float* bnp2 = alloc(256 * 512 * 2);
  float* Wp1f = alloc(9 * 80 * 256 / 2);
  float* Wp2f = alloc(9 * 256 * 96 / 2);
  unsigned short* Wp1 = (unsigned short*)Wp1f;
  unsigned short* Wp2 = (unsigned short*)Wp2f;
  // XT bf16 (8.39 MB) aliases Ua..qtA; dead after conv1, before stage1 writes Ua.
  unsigned short* XT = (unsigned short*)Ua;
  // MT bf16 (3.15 MB) aliases C0,prr,Ua,Ub — all dead after stage4; outmid reads none.
  unsigned short* MT = (unsigned short*)C0;

  // 1. transpose x + pack both weights
  pre_k<<<2608, 256, 0, stream>>>(x, w_norm, w_innorm, XT, Wp1, Wp2);
  // 2. conv1 (bf16 MFMA, BN1 partials in epilogue)
  conv_mfma_k<256, 128, 65, 80, 5, 1, 7><<<dim3(64, 8), 5 * 64, 0, stream>>>(XT, Wp1, b_norm, hb, bnp1);
  // 3. prep (redundant BN1 finalize + field split, XCD-swizzled)
  prep_k<<<384, 256, 0, stream>>>(hb, bnp1, gb, Fz, Fq, Fu, Fvf, Ft, zx, zy, zz, ux, vy, wvel, part1);
  // 4-7. RK stages (monolithic, XCD-aligned batch swizzle)
  stage_k<1><<<NF / 256, 256, 0, stream>>>(Fu, Fvf, Ft, Fu, Fvf, Ft, Fq, ux, vy, zx, zy, wvel, zz, part1,
      C0, prr, Ua, Va, Ta, duA, dvA, dtA, k4t, qtA, pduv, pdt, pqt, 0.5f * DT);
  stage_k<2><<<NF / 256, 256, 0, stream>>>(Ua, Va, Ta, Fu, Fvf, Ft, Fq, ux, vy, zx, zy, wvel, zz, part1,
      C0, prr, Ub, Vb, Tb, duA, dvA, dtA, k4t, qtA, pduv, pdt, pqt, 0.5f * DT);
  stage_k<3><<<NF / 256, 256, 0, stream>>>(Ub, Vb, Tb, Fu, Fvf, Ft, Fq, ux, vy, zx, zy, wvel, zz, part1,
      C0, prr, Ua, Va, Ta, duA, dvA, dtA, k4t, qtA, pduv, pdt, pqt, DT);
  stage_k<4><<<NF / 256, 256, 0, stream>>>(Ua, Va, Ta, Fu, Fvf, Ft, Fq, ux, vy, zx, zy, wvel, zz, part1,
      C0, prr, Ub, Vb, Tb, duA, dvA, dtA, k4t, qtA, pduv, pdt, pqt, 0.f);
  // 8. z-tendency integral (XCD-swizzled)
  zt_k<<<256, 64, 0, stream>>>(k4t, ztA, pzt);
  // 9. fused finalize + outmid + bf16 transpose (XCD-swizzled)
  outmid_fused_k<<<256, 256, 0, stream>>>(hb, Fz, Fq, Fu, Fvf, Ft, ztA, qtA, duA, dvA, dtA,
      coef, part1, pduv, pdt, pqt, pzt, MT);
  // 10. conv2 (BN2 partials in epilogue)
  conv_mfma_k<96, 96, 256, 256, 8, 2, 3><<<dim3(64, 8), 8 * 64, 0, stream>>>(MT, Wp2, b_innorm, yout, bnp2);
  // 11. redundant BN2 finalize + apply + residual
  final_k<<<4096, 256, 0, stream>>>(yout, x, bnp2, gblk, bblk);
}

// Round 13
// 158.778 us; speedup vs baseline: 1.3000x; 1.1194x over previous
//
#include <hip/hip_runtime.h>
#include <math.h>

#define DEVFN static __device__ __forceinline__

static constexpr int BB = 8, VV = 13, HH = 32, WW = 64;
static constexpr int NPLANE = HH * WW;        // 2048
static constexpr int NF = BB * VV * NPLANE;   // 212992
static constexpr int NHB = BB * 65 * NPLANE;  // 1064960

static constexpr float DT = 300.0f;
static constexpr float KHc = 15.0f, KVc = 0.1f;
static constexpr float OMEGAc = 7.29e-5f;
static constexpr float L_Vc = 2.5e6f;
static constexpr float R_GASc = 8.314f;
static constexpr float C_Pc = 1005.0f;
static constexpr float PTHc = 0.8f;
static constexpr double PYd = 3.14159265358979323846 * 6371000.0 / 33.0;
static constexpr float PYc  = (float)PYd;
static constexpr float PXCc = (float)(2.0 * 3.14159265358979323846 * 6371000.0 / 64.0);
static constexpr double RCCd = 0.7 * 5.67e-8 * 287.0 / (1005.0 * 100.0);
static constexpr float FBIG = 3.402823466e38f;

__constant__ float cDZ[13]  = {50,50,50,50,50,75,100,100,100,125,112,75,75};
// (1/12)/dz
__constant__ float cZI[13] = {
  (float)(1.0/600.0), (float)(1.0/600.0), (float)(1.0/600.0), (float)(1.0/600.0), (float)(1.0/600.0),
  (float)(1.0/900.0), (float)(1.0/1200.0), (float)(1.0/1200.0), (float)(1.0/1200.0),
  (float)(1.0/1500.0), (float)(1.0/1344.0), (float)(1.0/900.0), (float)(1.0/900.0)};
// -RCC/pressure
__constant__ float cRC[13] = {
  (float)(-RCCd/50.0), (float)(-RCCd/100.0), (float)(-RCCd/150.0), (float)(-RCCd/200.0),
  (float)(-RCCd/250.0), (float)(-RCCd/300.0), (float)(-RCCd/400.0), (float)(-RCCd/500.0),
  (float)(-RCCd/600.0), (float)(-RCCd/700.0), (float)(-RCCd/850.0), (float)(-RCCd/925.0),
  (float)(-RCCd/1000.0)};
// dz * (-R_GAS/pressure)
__constant__ float cZW[13] = {
  (float)(50.0*(-8.314/50.0)), (float)(50.0*(-8.314/100.0)), (float)(50.0*(-8.314/150.0)),
  (float)(50.0*(-8.314/200.0)), (float)(50.0*(-8.314/250.0)), (float)(75.0*(-8.314/300.0)),
  (float)(100.0*(-8.314/400.0)), (float)(100.0*(-8.314/500.0)), (float)(100.0*(-8.314/600.0)),
  (float)(125.0*(-8.314/700.0)), (float)(112.0*(-8.314/850.0)), (float)(75.0*(-8.314/925.0)),
  (float)(75.0*(-8.314/1000.0))};

// ===== compile-time composed stencil tables (pad-map folded, scales folded) =====
constexpr int pmhC(int r){ return r < 0 ? r + 2 : (r > 31 ? r - 2 : r); }
constexpr int pmvC(int r){ return r < 0 ? r + 2 : (r > 12 ? r - 2 : r); }

struct STab {
  float y1[32][9];   // d_y (scale 1/(12 PY) folded), col = h-4+k
  float y2[32][9];   // KH * dyy composed
  float z1[13][9];   // d_z (cZI folded), col = v-4+k
  float z2[13][9];   // KV * dzz composed
};

constexpr STab makeTab(){
  STab t = {};
  double A[32][32] = {};
  {
    for (int h = 0; h < 32; ++h){
      const double s = 1.0 / 12.0 / PYd;
      A[h][pmhC(h - 2)] += -s;
      A[h][pmhC(h - 1)] +=  8.0 * s;
      A[h][pmhC(h + 1)] += -8.0 * s;
      A[h][pmhC(h + 2)] +=  s;
    }
    for (int h = 0; h < 32; ++h)
      for (int k = 0; k < 9; ++k){
        int c = h - 4 + k;
        if (c >= 0 && c < 32){
          double m = 0.0;
          for (int j = 0; j < 32; ++j) m += A[h][j] * A[j][c];
          t.y2[h][k] = (float)(15.0 * m);      // KH folded
          t.y1[h][k] = (float)A[h][c];
        }
      }
  }
  {
    double dzv[13] = {50,50,50,50,50,75,100,100,100,125,112,75,75};
    double B[13][13] = {};
    for (int v = 0; v < 13; ++v){
      const double s = 1.0 / 12.0 / dzv[v];
      B[v][pmvC(v - 2)] += -s;
      B[v][pmvC(v - 1)] +=  8.0 * s;
      B[v][pmvC(v + 1)] += -8.0 * s;
      B[v][pmvC(v + 2)] +=  s;
    }
    for (int v = 0; v < 13; ++v)
      for (int k = 0; k < 9; ++k){
        int c = v - 4 + k;
        if (c >= 0 && c < 13){
          double m = 0.0;
          for (int j = 0; j < 13; ++j) m += B[v][j] * B[j][c];
          t.z2[v][k] = (float)(0.1 * m);       // KV folded
          t.z1[v][k] = (float)B[v][c];
        }
      }
  }
  return t;
}
__constant__ STab cT = makeTab();

typedef short bf16x8 __attribute__((ext_vector_type(8)));
typedef float f32x4 __attribute__((ext_vector_type(4)));

DEVFN int pmh(int r){ return r < 0 ? r + 2 : (r > HH - 1 ? r - 2 : r); }
DEVFN int pmv(int r){ return r < 0 ? r + 2 : (r > VV - 1 ? r - 2 : r); }
DEVFN float latOf(int h){ return (90.0f - (float)(h + 1) * (180.0f / 33.0f)) * 0.017453292519943295f; }
DEVFN float avoid_inf(float t){
  if (t == 0.0f) t = 0.1f;
  if (fabsf(t) < 1.0f) t = copysignf(1.0f, t);
  return t;
}
DEVFN unsigned short f2bf(float f){
  unsigned u = __float_as_uint(f);
  unsigned r = (u + 0x7fffu + ((u >> 16) & 1u)) >> 16;
  return (unsigned short)r;
}

// ---- x-direction stencils (per-lane w, periodic) ----
DEVFN float d_xf(const float* __restrict__ F, int rb, int w, float invpx){
  return (F[rb + ((w + 62) & 63)] - 8.f * F[rb + ((w + 63) & 63)]
        + 8.f * F[rb + ((w + 1) & 63)] - F[rb + ((w + 2) & 63)]) * (1.f / 12.f) * invpx;
}
DEVFN float dxxf(const float* __restrict__ F, int rb, int w, float invpx){
  float s = F[rb + ((w + 60) & 63)] - 16.f * F[rb + ((w + 61) & 63)] + 64.f * F[rb + ((w + 62) & 63)]
          + 16.f * F[rb + ((w + 63) & 63)] - 130.f * F[rb + w] + 16.f * F[rb + ((w + 1) & 63)]
          + 64.f * F[rb + ((w + 2) & 63)] - 16.f * F[rb + ((w + 3) & 63)] + F[rb + ((w + 4) & 63)];
  return s * (1.f / 144.f) * invpx * invpx;
}

// ---- fused (d, d2) table stencils; h/v wave-uniform -> scalar coeffs ----
DEVFN void dyPair(const float* __restrict__ F, const float* __restrict__ c1,
                  const float* __restrict__ c2, int bvbase, int h, int w,
                  float& dy, float& dyy){
  dy = 0.f; dyy = 0.f;
  #pragma unroll
  for (int k = 0; k < 9; ++k){
    int rr = h - 4 + k; rr = rr < 0 ? 0 : (rr > 31 ? 31 : rr);
    float val = F[bvbase + rr * 64 + w];
    dy  = fmaf(c1[k], val, dy);
    dyy = fmaf(c2[k], val, dyy);
  }
}
DEVFN void dzPair(const float* __restrict__ F, const float* __restrict__ c1,
                  const float* __restrict__ c2, int bbase, int v, int hw,
                  float& dz, float& dzz){
  dz = 0.f; dzz = 0.f;
  #pragma unroll
  for (int k = 0; k < 9; ++k){
    int rr = v - 4 + k; rr = rr < 0 ? 0 : (rr > 12 ? 12 : rr);
    float val = F[bbase + rr * 2048 + hw];
    dz  = fmaf(c1[k], val, dz);
    dzz = fmaf(c2[k], val, dzz);
  }
}

// ---- reductions ----
DEVFN float waveRedSum(float v){ for (int o = 32; o; o >>= 1) v += __shfl_down(v, o, 64); return v; }
DEVFN float waveRedMin(float v){ for (int o = 32; o; o >>= 1) v = fminf(v, __shfl_down(v, o, 64)); return v; }
DEVFN float waveRedMax(float v){ for (int o = 32; o; o >>= 1) v = fmaxf(v, __shfl_down(v, o, 64)); return v; }

template<int OP, int NWV>
static __device__ float blockRedN(float v){
  __shared__ float s[NWV];
  v = OP == 0 ? waveRedSum(v) : OP == 1 ? waveRedMin(v) : waveRedMax(v);
  int lane = threadIdx.x & 63, wid = threadIdx.x >> 6;
  __syncthreads();
  if (lane == 0) s[wid] = v;
  __syncthreads();
  float r = s[0];
  #pragma unroll
  for (int k = 1; k < NWV; ++k)
    r = OP == 0 ? r + s[k] : OP == 1 ? fminf(r, s[k]) : fmaxf(r, s[k]);
  return r;
}

struct GB { const float* g[5]; const float* b[5]; };

// ================= launch 1: transpose x + pack both weights =================
__global__ void __launch_bounds__(256) pre_k(const float* __restrict__ x,
    const float* __restrict__ w1, const float* __restrict__ w2,
    unsigned short* __restrict__ XT, unsigned short* __restrict__ wp1,
    unsigned short* __restrict__ wp2)
{
  int blk = blockIdx.x, t = threadIdx.x;
  if (blk < 1024){
    __shared__ float tile[16 * 68];
    int zz = blk >> 8, rem = blk & 255;
    int b = rem >> 5, h = rem & 31;
    for (int p = zz * 4; p < zz * 4 + 4; ++p){
      int cbase = p * 16;
      __syncthreads();
      {
        int cl = t >> 4, w4 = (t & 15) * 4;
        float4 v = *(const float4*)(x + (((size_t)(b * 256 + cbase + cl) * 32 + h) * 64 + w4));
        tile[cl * 68 + w4 + 0] = v.x; tile[cl * 68 + w4 + 1] = v.y;
        tile[cl * 68 + w4 + 2] = v.z; tile[cl * 68 + w4 + 3] = v.w;
      }
      __syncthreads();
      {
        int w = t >> 2, c4 = (t & 3) * 4;
        ushort4 o;
        o.x = f2bf(tile[(c4 + 0) * 68 + w]);
        o.y = f2bf(tile[(c4 + 1) * 68 + w]);
        o.z = f2bf(tile[(c4 + 2) * 68 + w]);
        o.w = f2bf(tile[(c4 + 3) * 68 + w]);
        *(ushort4*)(XT + (((size_t)(b * 32 + h) * 64 + w) * 256 + cbase + c4)) = o;
      }
    }
  } else {
    const int T1 = 9 * 80 * 256;
    const int T2 = 9 * 256 * 96;
    int idx = (blk - 1024) * 256 + t;
    if (idx < T1){
      int dir = idx / (80 * 256);
      int r = idx - dir * (80 * 256);
      int co = r / 256, ci = r - co * 256;
      float v = (co < 65) ? w1[((size_t)(co * 256 + ci)) * 9 + dir] : 0.f;
      wp1[idx] = f2bf(v);
    } else if (idx < T1 + T2){
      int j = idx - T1;
      int dir = j / (256 * 96);
      int r = j - dir * (256 * 96);
      int co = r / 96, ci = r - co * 96;
      float v = (ci < 65) ? w2[((size_t)(co * 65 + ci)) * 9 + dir] : 0.f;
      wp2[j] = f2bf(v);
    }
  }
}

// ================= conv via MFMA; 32-pixel blocks; BN partials in epilogue =================
template<int CIT, int CIL, int CO, int COp, int NW, int MF, int SWZ>
__global__ void __launch_bounds__(NW * 64) conv_mfma_k(
    const unsigned short* __restrict__ XT, const unsigned short* __restrict__ Wp,
    const float* __restrict__ bias, float* __restrict__ out, float* __restrict__ bnp)
{
  __shared__ __align__(16) unsigned short Xl[3 * 34 * CIL];
  const int C8 = CIL / 8;
  int tid = threadIdx.x;
  int bx = blockIdx.x, b = blockIdx.y;
  int h = bx >> 1, p0 = (bx & 1) << 5;
  int bh = b * 64 + bx;
  int wid = tid >> 6, lane = tid & 63;
  int l15 = lane & 15, q = lane >> 4;

  f32x4 acc[MF][2];
  #pragma unroll
  for (int mf = 0; mf < MF; ++mf)
    #pragma unroll
    for (int nf = 0; nf < 2; ++nf){ f32x4 z = {0.f, 0.f, 0.f, 0.f}; acc[mf][nf] = z; }

  for (int cp = 0; cp < CIT / CIL; ++cp){
    if (cp) __syncthreads();
    for (int idx = tid; idx < 3 * 34 * C8; idx += NW * 64){
      int r = idx / (34 * C8);
      int rest = idx - r * (34 * C8);
      int j = rest / C8;
      int c8 = rest - j * C8;
      int hh = h + r - 1;
      int gw = p0 - 1 + j;
      uint4 val = make_uint4(0, 0, 0, 0);
      if (hh >= 0 && hh < 32 && gw >= 0 && gw < 64)
        val = *(const uint4*)(XT + (((size_t)(b * 32 + hh) * 64 + gw) * CIT + cp * CIL + c8 * 8));
      int dst = (r * 34 + j) * CIL + ((c8 * 8) ^ ((j & SWZ) << 3));
      *(uint4*)(Xl + dst) = val;
    }
    __syncthreads();

    for (int dir = 0; dir < 9; ++dir){
      int dy = dir / 3, dx = dir - dy * 3;
      #pragma unroll
      for (int kc = 0; kc < CIL / 32; ++kc){
        int kb = kc * 32 + q * 8;
        bf16x8 a[MF];
        #pragma unroll
        for (int mf = 0; mf < MF; ++mf){
          int co = wid * (MF * 16) + mf * 16 + l15;
          a[mf] = *(const bf16x8*)(Wp + ((size_t)(dir * COp + co) * CIT + cp * CIL + kb));
        }
        #pragma unroll
        for (int nf = 0; nf < 2; ++nf){
          int j = nf * 16 + l15 + dx;
          bf16x8 bfrag = *(const bf16x8*)(Xl + ((dy * 34 + j) * CIL + (kb ^ ((j & SWZ) << 3))));
          #pragma unroll
          for (int mf = 0; mf < MF; ++mf)
            acc[mf][nf] = __builtin_amdgcn_mfma_f32_16x16x32_bf16(a[mf], bfrag, acc[mf][nf], 0, 0, 0);
        }
      }
    }
  }
  #pragma unroll
  for (int mf = 0; mf < MF; ++mf){
    #pragma unroll
    for (int r = 0; r < 4; ++r){
      int co = wid * (MF * 16) + mf * 16 + q * 4 + r;
      if (CO != COp && co >= CO) continue;
      float bv = bias[co];
      float sv = 0.f, sq = 0.f;
      #pragma unroll
      for (int nf = 0; nf < 2; ++nf){
        int pix = nf * 16 + l15;
        float val = acc[mf][nf][r] + bv;
        out[(size_t)(b * CO + co) * 2048 + h * 64 + p0 + pix] = val;
        sv += val; sq += val * val;
      }
      #pragma unroll
      for (int off = 8; off; off >>= 1){
        sv += __shfl_xor(sv, off, 16);
        sq += __shfl_xor(sq, off, 16);
      }
      if (l15 == 0){
        bnp[((size_t)co * 512 + bh) * 2]     = sv;
        bnp[((size_t)co * 512 + bh) * 2 + 1] = sq;
      }
    }
  }
}

// ================= prep: BN1 finalize (redundant) + field prep, XCD-swizzled =================
__global__ void __launch_bounds__(256) prep_k(const float* __restrict__ hb,
  const float* __restrict__ bnp1, GB gb,
  float* __restrict__ Fz, float* __restrict__ Fq, float* __restrict__ Fu,
  float* __restrict__ Fvf, float* __restrict__ Ft,
  float* __restrict__ zx, float* __restrict__ zy, float* __restrict__ zz,
  float* __restrict__ ux, float* __restrict__ vy, float* __restrict__ wv,
  float* __restrict__ partS)
{
  __shared__ float As[65], Bs[65];
  int blk = blockIdx.x, t = threadIdx.x;
  {
    int wvid = t >> 6, lane = t & 63;
    for (int ch = wvid; ch < 65; ch += 4){
      const float4* pp = (const float4*)(bnp1 + (size_t)ch * 1024) + lane * 4;
      float s = 0.f, sq = 0.f;
      #pragma unroll
      for (int k = 0; k < 4; ++k){ float4 v = pp[k]; s += v.x + v.z; sq += v.y + v.w; }
      s = waveRedSum(s); sq = waveRedSum(sq);
      if (!lane){
        float m = s * (1.f / 16384.f);
        float var = sq * (1.f / 16384.f) - m * m;
        float rstd = rsqrtf(var + 1e-5f);
        int f = ch / 13, k = ch - f * 13;
        float g = gb.g[f][k], bbv = gb.b[f][k];
        As[ch] = g * rstd; Bs[ch] = bbv - m * g * rstd;
      }
    }
  }
  __syncthreads();

  int part = blk >> 6;
  int chunk = blk & 63;
  int b = chunk & 7;                       // XCD-aligned: blk%8 fixes batch
  int p = ((chunk >> 3) << 8) | t;         // 8 chunks x 256 = 2048 pixels
  int h = p >> 6, w = p & 63;
  int hbase = b * 65 * NPLANE;
  auto hn = [&](int ch, int hh, int ww)->float {
    return hb[hbase + ch * 2048 + hh * 64 + ww] * As[ch] + Bs[ch];
  };
  int fb = (b * 13) * 2048 + p;
  float lat = latOf(h);
  float invpx = 1.0f / (PXCc * cosf(lat));
  int wm2 = (w + 62) & 63, wm1 = (w + 63) & 63, wpl1 = (w + 1) & 63, wpl2 = (w + 2) & 63;
  int hm2 = pmh(h - 2), hm1 = pmh(h - 1), hp1 = pmh(h + 1), hp2 = pmh(h + 2);
  float fmn = FBIG, fmx = -FBIG, fsm = 0.f, smn = FBIG, smx = -FBIG;
  if (part < 5){
    int ch0 = part * 13;
    float c[13];
    #pragma unroll
    for (int v = 0; v < 13; ++v) c[v] = hn(ch0 + v, h, w);
    float* Fdst = part == 0 ? Fz : part == 1 ? Fq : part == 2 ? Fu : part == 3 ? Fvf : Ft;
    #pragma unroll
    for (int v = 0; v < 13; ++v) Fdst[fb + v * 2048] = c[v];
    if (part == 0){
      #pragma unroll
      for (int v = 0; v < 13; ++v){
        zz[fb + v * 2048] = (-c[pmv(v - 2)] + 8.f * c[pmv(v - 1)] - 8.f * c[pmv(v + 1)] + c[pmv(v + 2)]) * cZI[v];
        float zxv = (hn(v, h, wm2) - 8.f * hn(v, h, wm1) + 8.f * hn(v, h, wpl1) - hn(v, h, wpl2)) * (1.f / 12.f) * invpx;
        float zyv = (-hn(v, hm2, w) + 8.f * hn(v, hm1, w) - 8.f * hn(v, hp1, w) + hn(v, hp2, w)) * (1.f / 12.f) * (1.f / PYc);
        zx[fb + v * 2048] = zxv; zy[fb + v * 2048] = zyv;
      }
    }
    if (part == 2){
      #pragma unroll
      for (int v = 0; v < 13; ++v){
        float uxv = (hn(26 + v, h, wm2) - 8.f * hn(26 + v, h, wm1) + 8.f * hn(26 + v, h, wpl1) - hn(26 + v, h, wpl2)) * (1.f / 12.f) * invpx;
        ux[fb + v * 2048] = uxv;
      }
    }
    if (part == 3){
      #pragma unroll
      for (int v = 0; v < 13; ++v){
        float vyv = (-hn(39 + v, hm2, w) + 8.f * hn(39 + v, hm1, w) - 8.f * hn(39 + v, hp1, w) + hn(39 + v, hp2, w)) * (1.f / 12.f) * (1.f / PYc);
        vy[fb + v * 2048] = vyv;
      }
    }
    if (part == 4){
      #pragma unroll
      for (int v = 0; v < 13; ++v){
        float tcc = c[v] - 273.15f;
        float arg = 17.67f * tcc / avoid_inf(tcc + 243.5f);
        smn = fminf(smn, arg); smx = fmaxf(smx, arg);
      }
    }
    #pragma unroll
    for (int v = 0; v < 13; ++v){ fmn = fminf(fmn, c[v]); fmx = fmaxf(fmx, c[v]); fsm += c[v]; }
  } else {
    float cum = 0.f;
    #pragma unroll
    for (int v = 0; v < 13; ++v){
      float uxv = (hn(26 + v, h, wm2) - 8.f * hn(26 + v, h, wm1) + 8.f * hn(26 + v, h, wpl1) - hn(26 + v, h, wpl2)) * (1.f / 12.f) * invpx;
      float vyv = (-hn(39 + v, hm2, w) + 8.f * hn(39 + v, hm1, w) - 8.f * hn(39 + v, hp1, w) + hn(39 + v, hp2, w)) * (1.f / 12.f) * (1.f / PYc);
      cum += cDZ[v] * (uxv + vyv);
      wv[fb + v * 2048] = -cum;
    }
  }
  float* pb = partS + blk * 17;
  float r;
  r = blockRedN<1,4>(smn); if (!t) pb[0] = r;
  r = blockRedN<2,4>(smx); if (!t) pb[1] = r;
  #pragma unroll
  for (int f = 0; f < 5; ++f){
    r = blockRedN<1,4>(part == f ? fmn : FBIG);  if (!t) pb[2 + f * 3] = r;
    r = blockRedN<2,4>(part == f ? fmx : -FBIG); if (!t) pb[3 + f * 3] = r;
    r = blockRedN<0,4>(part == f ? fsm : 0.f);   if (!t) pb[4 + f * 3] = r;
  }
}

// ===== merged RK stage (monolithic u+v+t), XCD swizzle + composed stencil tables =====
template<int STAGE>
__global__ void __launch_bounds__(256) stage_k(
  const float* __restrict__ U, const float* __restrict__ Vf, const float* __restrict__ T,
  const float* __restrict__ Fu, const float* __restrict__ Fvf, const float* __restrict__ Ft,
  const float* __restrict__ Fq,
  const float* __restrict__ ux, const float* __restrict__ vy,
  const float* __restrict__ zx, const float* __restrict__ zy,
  const float* __restrict__ wv, const float* __restrict__ zz,
  const float* __restrict__ partS,
  float* C0, float* prr,
  float* Uo, float* Vo, float* To,
  float* duA, float* dvA, float* dtA, float* k4t, float* qtA,
  float* pduv, float* pdt, float* pqt, float cnext)
{
  float ss = 0.f, off = 0.f;
  if (STAGE == 1){
    int tt = threadIdx.x;
    float v0 = partS[tt * 17], v1 = partS[tt * 17 + 1];
    if (tt < 128){
      v0 = fminf(v0, partS[(tt + 256) * 17]);
      v1 = fmaxf(v1, partS[(tt + 256) * 17 + 1]);
    }
    float smn = blockRedN<1,4>(v0);
    float smx = blockRedN<2,4>(v1);
    ss = (3.01f + 3.47f) / (smx - smn);
    off = -3.47f - smn * ss;
  }
  int blk = blockIdx.x, t = threadIdx.x;
  int b = blk & 7;
  int rest = blk >> 3;          // 0..103
  int v = rest % 13;
  int hg = rest / 13;           // 0..7
  int h = (hg << 2) | (t >> 6);
  int w = t & 63;
  int bv = b * 13 + v;
  int bvbase = bv * 2048;
  int rb = bvbase + h * 64;
  int bbase = b * 13 * 2048;
  int hw = h * 64 + w;
  int i = bvbase + hw;
  float lat = latOf(h);
  float invpx = 1.0f / (PXCc * cosf(lat));
  float fcor = 2.0f * OMEGAc * sinf(lat);
  float wvi = wv[i];
  float Ui = U[i], Vi = Vf[i], Ti = T[i];
  float Fui = (STAGE == 1) ? Ui : Fu[i];
  float Fvi = (STAGE == 1) ? Vi : Fvf[i];

  const float* y1 = cT.y1[h];
  const float* y2 = cT.y2[h];
  const float* z1 = cT.z1[v];
  const float* z2 = cT.z2[v];

  // ---- u tendency ----
  float dyU, dyyU, dzU, dzzU;
  dyPair(U, y1, y2, bvbase, h, w, dyU, dyyU);
  dzPair(U, z1, z2, bbase, v, hw, dzU, dzzU);
  float mixU = KHc * dxxf(U, rb, w, invpx) + dyyU + dzzU;
  float ku = -Ui * ux[i] - Vi * dyU - wvi * dzU + fcor * Vi - zx[i] + mixU;

  // ---- v tendency ----
  float dyVd, dyyV, dzV, dzzV;
  dyPair(Vf, y1, y2, bvbase, h, w, dyVd, dyyV);
  dzPair(Vf, z1, z2, bbase, v, hw, dzV, dzzV);
  float dxV = d_xf(Vf, rb, w, invpx);
  float mixV = KHc * dxxf(Vf, rb, w, invpx) + dyyV + dzzV;
  float kv = -Ui * dxV - Vi * vy[i] - wvi * dzV - fcor * Ui - zy[i] + mixV;

  // ---- C0 ----
  float C0i;
  if (STAGE == 1){
    float zzi = zz[i], qi = Fq[i];
    float rho = -1.0f / avoid_inf(zzi);
    float p = rho * R_GASc * Ti;               // Ti == Ft at stage 1
    float tcc = Ti - 273.15f;
    float arg = 17.67f * tcc / avoid_inf(tcc + 243.5f);
    float es = 6.112f * expf(arg * ss + off) * 100.0f;
    float qs = fmaxf(0.622f * es / avoid_inf(p - 0.378f * es), 1e-6f);
    float rh = qi / avoid_inf(qs);
    float rate = (rh > PTHc) ? (qi - PTHc * qs) * (1.0f / DT) : 0.0f;
    prr[i] = rate;
    C0i = -(L_Vc + 1.0f) * zzi * wvi * (1.0f / C_Pc) + rate * (L_Vc / C_Pc);
    C0[i] = C0i;
  } else {
    C0i = C0[i];
  }

  // ---- t tendency ----
  float dyT, dyyT, dzT, dzzT;
  dyPair(T, y1, y2, bvbase, h, w, dyT, dyyT);
  dzPair(T, z1, z2, bbase, v, hw, dzT, dzzT);
  float dxT = d_xf(T, rb, w, invpx);
  float mixT = KHc * dxxf(T, rb, w, invpx) + dyyT + dzzT;
  float ta = Ti + 273.15f;
  float t2 = ta * ta;
  float ta5 = t2 * t2 * ta;
  float rc = cRC[v] * ta5;
  float kt = C0i - Fui * dxT - Fvi * dyT - wvi * dzT + mixT + rc;

  if (STAGE == 1){ duA[i] = ku; dvA[i] = kv; dtA[i] = kt; }
  else if (STAGE < 4){ duA[i] += 2.f * ku; dvA[i] += 2.f * kv; dtA[i] += 2.f * kt; }
  else {
    float au = duA[i] + ku, av = dvA[i] + kv, at = dtA[i] + kt;
    duA[i] = au; dvA[i] = av; dtA[i] = at; k4t[i] = kt;
    float m0 = blockRedN<1,4>(au), m1 = blockRedN<2,4>(au);
    float m2 = blockRedN<1,4>(av), m3 = blockRedN<2,4>(av);
    float m4 = blockRedN<1,4>(at), m5 = blockRedN<2,4>(at);
    if (!t){
      float* pp = pduv + blk * 4;
      pp[0] = m0; pp[1] = m1; pp[2] = m2; pp[3] = m3;
      pdt[blk * 2] = m4; pdt[blk * 2 + 1] = m5;
    }
  }
  if (STAGE < 4){
    float Fti = (STAGE == 1) ? Ti : Ft[i];
    Uo[i] = Fui + cnext * ku;
    Vo[i] = Fvi + cnext * kv;
    To[i] = Fti + cnext * kt;
  }

  if (STAGE == 2){
    float dyQ, dyyQ, dzQ, dzzQ;
    dyPair(Fq, y1, y2, bvbase, h, w, dyQ, dyyQ);
    dzPair(Fq, z1, z2, bbase, v, hw, dzQ, dzzQ);
    float mixQ = KHc * dxxf(Fq, rb, w, invpx) + dyyQ + dzzQ;
    float qtv = -Fui * d_xf(Fq, rb, w, invpx) - Fvi * dyQ - wvi * dzQ + mixQ - prr[i];
    qtA[i] = qtv;
    float m0 = blockRedN<1,4>(qtv), m1 = blockRedN<2,4>(qtv);
    if (!t){ pqt[blk * 2] = m0; pqt[blk * 2 + 1] = m1; }
  }
}

__global__ void __launch_bounds__(64) zt_k(const float* __restrict__ k4t, float* __restrict__ zt, float* __restrict__ pmm)
{
  int blk = blockIdx.x;
  int b = blk & 7;                        // XCD-aligned batch
  int p = ((blk >> 3) << 6) + threadIdx.x;
  int fb = b * 13 * 2048 + p;
  float cum = 0.f, mn = FBIG, mx = -FBIG;
  #pragma unroll
  for (int v = 0; v < 13; ++v){
    cum += cZW[v] * k4t[fb + v * 2048];
    zt[fb + v * 2048] = cum;
    mn = fminf(mn, cum); mx = fmaxf(mx, cum);
  }
  mn = waveRedMin(mn); mx = waveRedMax(mx);
  if (!threadIdx.x){ pmm[blk * 2] = mn; pmm[blk * 2 + 1] = mx; }
}

// ===== fused: redundant sc2 finalize + outmid (LDS tile) + bf16 transpose out =====
__global__ void __launch_bounds__(256) outmid_fused_k(
  const float* __restrict__ hb,
  const float* __restrict__ Fz, const float* __restrict__ Fq, const float* __restrict__ Fu,
  const float* __restrict__ Fvf, const float* __restrict__ Ft,
  const float* __restrict__ ztA, const float* __restrict__ qtA,
  const float* __restrict__ duA, const float* __restrict__ dvA, const float* __restrict__ dtA,
  const float* __restrict__ coef, const float* __restrict__ partS,
  const float* __restrict__ pduv, const float* __restrict__ pdt,
  const float* __restrict__ pqt, const float* __restrict__ pzt,
  unsigned short* __restrict__ MT)
{
  __shared__ float tileBig[65 * 66];
  int blk = blockIdx.x, t = threadIdx.x;

  float fmn[5] = {FBIG, FBIG, FBIG, FBIG, FBIG};
  float fmx[5] = {-FBIG, -FBIG, -FBIG, -FBIG, -FBIG};
  float fsm[5] = {0.f, 0.f, 0.f, 0.f, 0.f};
  #pragma unroll 1
  for (int r0 = t; r0 < 384; r0 += 256){
    const float* pr = partS + r0 * 17;
    #pragma unroll
    for (int f = 0; f < 5; ++f){
      fmn[f] = fminf(fmn[f], pr[2 + f * 3]);
      fmx[f] = fmaxf(fmx[f], pr[3 + f * 3]);
      fsm[f] += pr[4 + f * 3];
    }
  }
  #pragma unroll
  for (int f = 0; f < 5; ++f){
    fmn[f] = blockRedN<1,4>(fmn[f]);
    fmx[f] = blockRedN<2,4>(fmx[f]);
    fsm[f] = blockRedN<0,4>(fsm[f]);
  }
  float dumn = FBIG, dumx = -FBIG, dvmn = FBIG, dvmx = -FBIG, dtmn = FBIG, dtmx = -FBIG;
  float qmn = FBIG, qmx = -FBIG;
  #pragma unroll 1
  for (int r0 = t; r0 < 832; r0 += 256){
    dumn = fminf(dumn, pduv[r0 * 4]);     dumx = fmaxf(dumx, pduv[r0 * 4 + 1]);
    dvmn = fminf(dvmn, pduv[r0 * 4 + 2]); dvmx = fmaxf(dvmx, pduv[r0 * 4 + 3]);
    dtmn = fminf(dtmn, pdt[r0 * 2]);      dtmx = fmaxf(dtmx, pdt[r0 * 2 + 1]);
    qmn = fminf(qmn, pqt[r0 * 2]);        qmx = fmaxf(qmx, pqt[r0 * 2 + 1]);
  }
  float zmn = pzt[t * 2], zmx = pzt[t * 2 + 1];
  dumn = blockRedN<1,4>(dumn); dumx = blockRedN<2,4>(dumx);
  dvmn = blockRedN<1,4>(dvmn); dvmx = blockRedN<2,4>(dvmx);
  dtmn = blockRedN<1,4>(dtmn); dtmx = blockRedN<2,4>(dtmx);
  qmn = blockRedN<1,4>(qmn);   qmx = blockRedN<2,4>(qmx);
  zmn = blockRedN<1,4>(zmn);   zmx = blockRedN<2,4>(zmx);

  float scf[5], off2[5];
  {
    float rmn[5] = {zmn, qmn, dumn, dvmn, dtmn};
    float rmx[5] = {zmx, qmx, dumx, dvmx, dtmx};
    float cfs[5] = {DT, DT, DT / 6.f, DT / 6.f, DT / 6.f};
    #pragma unroll
    for (int f = 0; f < 5; ++f){
      float mnf = fmn[f], mef = fsm[f] * (1.0f / (float)NF), mxf = fmx[f];
      float aa = (mnf - mef) * 0.05f, b2 = (mxf - mef) * 0.05f;
      float cf = cfs[f];
      float dmn = rmn[f] * cf, dmx = rmx[f] * cf;
      float s = (b2 - aa) / (dmx - dmn);
      scf[f] = s * cf; off2[f] = aa - dmn * s;
    }
  }

  int b = blk & 7, h = blk >> 3;          // XCD-aligned batch
  #pragma unroll 1
  for (int idx = t; idx < 65 * 64; idx += 256){
    int c = idx >> 6, w = idx & 63;
    int f = c / 13, v = c - f * 13;
    int fi = (b * 13 + v) * 2048 + h * 64 + w;
    const float *Fp, *Rp;
    switch (f){
      case 0: Fp = Fz;  Rp = ztA; break;
      case 1: Fp = Fq;  Rp = qtA; break;
      case 2: Fp = Fu;  Rp = duA; break;
      case 3: Fp = Fvf; Rp = dvA; break;
      default: Fp = Ft; Rp = dtA; break;
    }
    float phys = Fp[fi] + Rp[fi] * scf[f] + off2[f];
    float cf = coef[c * 2048 + h * 64 + w];
    float hbv = hb[((size_t)(b * 65 + c)) * 2048 + h * 64 + w];
    tileBig[c * 66 + w] = cf * phys + (1.0f - cf) * hbv;
  }
  __syncthreads();
  #pragma unroll 1
  for (int ph = 0; ph < 6; ++ph){
    int cbase = ph * 16;
    int w = t >> 2, c4 = (t & 3) * 4;
    int c0 = cbase + c4;
    ushort4 o;
    o.x = (c0 + 0 < 65) ? f2bf(tileBig[(c0 + 0) * 66 + w]) : (unsigned short)0;
    o.y = (c0 + 1 < 65) ? f2bf(tileBig[(c0 + 1) * 66 + w]) : (unsigned short)0;
    o.z = (c0 + 2 < 65) ? f2bf(tileBig[(c0 + 2) * 66 + w]) : (unsigned short)0;
    o.w = (c0 + 3 < 65) ? f2bf(tileBig[(c0 + 3) * 66 + w]) : (unsigned short)0;
    *(ushort4*)(MT + (((size_t)(b * 32 + h) * 64 + w) * 96 + c0)) = o;
  }
}

// ===== final: redundant BN2 finalize + apply BN + residual =====
__global__ void __launch_bounds__(256) final_k(float* __restrict__ y, const float* __restrict__ x,
  const float* __restrict__ bnp2, const float* __restrict__ gblk, const float* __restrict__ bblk)
{
  int blk = blockIdx.x, t = threadIdx.x;
  int c = (blk >> 1) & 255;
  float4 pv = ((const float4*)(bnp2 + (size_t)c * 1024))[t];
  float s = pv.x + pv.z, sq = pv.y + pv.w;
  s = blockRedN<0,4>(s); sq = blockRedN<0,4>(sq);
  float m = s * (1.0f / 16384.0f);
  float var = sq * (1.0f / 16384.0f) - m * m;
  float rstd = rsqrtf(var + 1e-5f);
  float a = gblk[c] * rstd, bb = bblk[c] - m * gblk[c] * rstd;
  int e4 = blk * 256 + t;
  float4 v = ((const float4*)y)[e4];
  float4 xv = ((const float4*)x)[e4];
  v.x = v.x * a + bb + xv.x;
  v.y = v.y * a + bb + xv.y;
  v.z = v.z * a + bb + xv.z;
  v.w = v.w * a + bb + xv.w;
  ((float4*)y)[e4] = v;
}

extern "C" void kernel_launch(void* const* d_in, const int* in_sizes, int n_in,
                              void* d_out, int out_size, void* d_ws, size_t ws_size,
                              hipStream_t stream)
{
  (void)in_sizes; (void)n_in; (void)out_size; (void)ws_size;
  const float* x        = (const float*)d_in[0];
  const float* w_norm   = (const float*)d_in[1];
  const float* b_norm   = (const float*)d_in[2];
  const float* w_innorm = (const float*)d_in[3];
  const float* b_innorm = (const float*)d_in[4];
  const float* coef     = (const float*)d_in[5];
  GB gb;
  for (int f = 0; f < 5; ++f){
    gb.g[f] = (const float*)d_in[6 + 2 * f];
    gb.b[f] = (const float*)d_in[7 + 2 * f];
  }
  const float* gblk = (const float*)d_in[16];
  const float* bblk = (const float*)d_in[17];
  float* yout = (float*)d_out;

  float* ws = (float*)d_ws;
  size_t off = 0;
  auto alloc = [&](size_t n){ float* p = ws + off; off += n; return p; };
  float* hb  = alloc(NHB);
  float* Fz  = alloc(NF); float* Fq  = alloc(NF); float* Fu  = alloc(NF);
  float* Fvf = alloc(NF); float* Ft  = alloc(NF);
  float* zx  = alloc(NF); float* zy  = alloc(NF); float* zz  = alloc(NF);
  float* ux  = alloc(NF); float* vy  = alloc(NF); float* wvel = alloc(NF);
  float* C0  = alloc(NF); float* prr = alloc(NF);
  float* Ua  = alloc(NF); float* Ub  = alloc(NF); float* Va  = alloc(NF); float* Vb = alloc(NF);
  float* Ta  = alloc(NF); float* Tb  = alloc(NF);
  float* duA = alloc(NF); float* dvA = alloc(NF); float* dtA = alloc(NF);
  float* k4t = alloc(NF); float* ztA = alloc(NF); float* qtA = alloc(NF);
  float* part1 = alloc(384 * 17 + 4);
  float* pduv = alloc(832 * 4); float* pdt = alloc(832 * 2);
  float* pqt  = alloc(832 * 2); float* pzt = alloc(256 * 2);
  float* bnp1 = alloc(65 * 512 * 2);
  float* bnp2 = alloc(256 * 512 * 2);
  float* Wp1f = alloc(9 * 80 * 256 / 2);
  float* Wp2f = alloc(9 * 256 * 96 / 2);
  unsigned short* Wp1 = (unsigned short*)Wp1f;
  unsigned short* Wp2 = (unsigned short*)Wp2f;
  // XT bf16 (8.39 MB) aliases Ua..qtA; dead after conv1, before stage1 writes Ua.
  unsigned short* XT = (unsigned short*)Ua;
  // MT bf16 (3.15 MB) aliases C0,prr,Ua,Ub — all dead after stage4; outmid reads none.
  unsigned short* MT = (unsigned short*)C0;

  // 1. transpose x + pack both weights
  pre_k<<<2608, 256, 0, stream>>>(x, w_norm, w_innorm, XT, Wp1, Wp2);
  // 2. conv1 (bf16 MFMA, BN1 partials in epilogue)
  conv_mfma_k<256, 128, 65, 80, 5, 1, 7><<<dim3(64, 8), 5 * 64, 0, stream>>>(XT, Wp1, b_norm, hb, bnp1);
  // 3. prep (redundant BN1 finalize + field split, XCD-swizzled)
  prep_k<<<384, 256, 0, stream>>>(hb, bnp1, gb, Fz, Fq, Fu, Fvf, Ft, zx, zy, zz, ux, vy, wvel, part1);
  // 4-7. RK stages (monolithic, XCD swizzle, composed stencil tables)
  stage_k<1><<<NF / 256, 256, 0, stream>>>(Fu, Fvf, Ft, Fu, Fvf, Ft, Fq, ux, vy, zx, zy, wvel, zz, part1,
      C0, prr, Ua, Va, Ta, duA, dvA, dtA, k4t, qtA, pduv, pdt, pqt, 0.5f * DT);
  stage_k<2><<<NF / 256, 256, 0, stream>>>(Ua, Va, Ta, Fu, Fvf, Ft, Fq, ux, vy, zx, zy, wvel, zz, part1,
      C0, prr, Ub, Vb, Tb, duA, dvA, dtA, k4t, qtA, pduv, pdt, pqt, 0.5f * DT);
  stage_k<3><<<NF / 256, 256, 0, stream>>>(Ub, Vb, Tb, Fu, Fvf, Ft, Fq, ux, vy, zx, zy, wvel, zz, part1,
      C0, prr, Ua, Va, Ta, duA, dvA, dtA, k4t, qtA, pduv, pdt, pqt, DT);
  stage_k<4><<<NF / 256, 256, 0, stream>>>(Ua, Va, Ta, Fu, Fvf, Ft, Fq, ux, vy, zx, zy, wvel, zz, part1,
      C0, prr, Ub, Vb, Tb, duA, dvA, dtA, k4t, qtA, pduv, pdt, pqt, 0.f);
  // 8. z-tendency integral (XCD-swizzled)
  zt_k<<<256, 64, 0, stream>>>(k4t, ztA, pzt);
  // 9. fused finalize + outmid + bf16 transpose (XCD-swizzled)
  outmid_fused_k<<<256, 256, 0, stream>>>(hb, Fz, Fq, Fu, Fvf, Ft, ztA, qtA, duA, dvA, dtA,
      coef, part1, pduv, pdt, pqt, pzt, MT);
  // 10. conv2 (BN2 partials in epilogue)
  conv_mfma_k<96, 96, 256, 256, 8, 2, 3><<<dim3(64, 8), 8 * 64, 0, stream>>>(MT, Wp2, b_innorm, yout, bnp2);
  // 11. redundant BN2 finalize + apply + residual
  final_k<<<4096, 256, 0, stream>>>(yout, x, bnp2, gblk, bblk);
}

// Round 14
// 153.311 us; speedup vs baseline: 1.3463x; 1.0357x over previous
//
#include <hip/hip_runtime.h>
#include <math.h>

#define DEVFN static __device__ __forceinline__

static constexpr int BB = 8, VV = 13, HH = 32, WW = 64;
static constexpr int NPLANE = HH * WW;        // 2048
static constexpr int NF = BB * VV * NPLANE;   // 212992
static constexpr int NHB = BB * 65 * NPLANE;  // 1064960

static constexpr float DT = 300.0f;
static constexpr float KHc = 15.0f, KVc = 0.1f;
static constexpr float OMEGAc = 7.29e-5f;
static constexpr float L_Vc = 2.5e6f;
static constexpr float R_GASc = 8.314f;
static constexpr float C_Pc = 1005.0f;
static constexpr float PTHc = 0.8f;
static constexpr double PYd = 3.14159265358979323846 * 6371000.0 / 33.0;
static constexpr float PYc  = (float)PYd;
static constexpr float PXCc = (float)(2.0 * 3.14159265358979323846 * 6371000.0 / 64.0);
static constexpr double RCCd = 0.7 * 5.67e-8 * 287.0 / (1005.0 * 100.0);
static constexpr float FBIG = 3.402823466e38f;

__constant__ float cDZ[13]  = {50,50,50,50,50,75,100,100,100,125,112,75,75};
__constant__ float cZI[13] = {
  (float)(1.0/600.0), (float)(1.0/600.0), (float)(1.0/600.0), (float)(1.0/600.0), (float)(1.0/600.0),
  (float)(1.0/900.0), (float)(1.0/1200.0), (float)(1.0/1200.0), (float)(1.0/1200.0),
  (float)(1.0/1500.0), (float)(1.0/1344.0), (float)(1.0/900.0), (float)(1.0/900.0)};
__constant__ float cRC[13] = {
  (float)(-RCCd/50.0), (float)(-RCCd/100.0), (float)(-RCCd/150.0), (float)(-RCCd/200.0),
  (float)(-RCCd/250.0), (float)(-RCCd/300.0), (float)(-RCCd/400.0), (float)(-RCCd/500.0),
  (float)(-RCCd/600.0), (float)(-RCCd/700.0), (float)(-RCCd/850.0), (float)(-RCCd/925.0),
  (float)(-RCCd/1000.0)};
__constant__ float cZW[13] = {
  (float)(50.0*(-8.314/50.0)), (float)(50.0*(-8.314/100.0)), (float)(50.0*(-8.314/150.0)),
  (float)(50.0*(-8.314/200.0)), (float)(50.0*(-8.314/250.0)), (float)(75.0*(-8.314/300.0)),
  (float)(100.0*(-8.314/400.0)), (float)(100.0*(-8.314/500.0)), (float)(100.0*(-8.314/600.0)),
  (float)(125.0*(-8.314/700.0)), (float)(112.0*(-8.314/850.0)), (float)(75.0*(-8.314/925.0)),
  (float)(75.0*(-8.314/1000.0))};

// ===== compile-time composed stencil tables (pad-map folded, scales folded) =====
constexpr int pmhC(int r){ return r < 0 ? r + 2 : (r > 31 ? r - 2 : r); }
constexpr int pmvC(int r){ return r < 0 ? r + 2 : (r > 12 ? r - 2 : r); }

struct STab {
  float y1[32][9];   // d_y (scale 1/(12 PY) folded), col = h-4+k
  float y2[32][9];   // KH * dyy composed
  float z1[13][9];   // d_z (cZI folded), col = v-4+k
  float z2[13][9];   // KV * dzz composed
};

constexpr STab makeTab(){
  STab t = {};
  double A[32][32] = {};
  {
    for (int h = 0; h < 32; ++h){
      const double s = 1.0 / 12.0 / PYd;
      A[h][pmhC(h - 2)] += -s;
      A[h][pmhC(h - 1)] +=  8.0 * s;
      A[h][pmhC(h + 1)] += -8.0 * s;
      A[h][pmhC(h + 2)] +=  s;
    }
    for (int h = 0; h < 32; ++h)
      for (int k = 0; k < 9; ++k){
        int c = h - 4 + k;
        if (c >= 0 && c < 32){
          double m = 0.0;
          for (int j = 0; j < 32; ++j) m += A[h][j] * A[j][c];
          t.y2[h][k] = (float)(15.0 * m);      // KH folded
          t.y1[h][k] = (float)A[h][c];
        }
      }
  }
  {
    double dzv[13] = {50,50,50,50,50,75,100,100,100,125,112,75,75};
    double B[13][13] = {};
    for (int v = 0; v < 13; ++v){
      const double s = 1.0 / 12.0 / dzv[v];
      B[v][pmvC(v - 2)] += -s;
      B[v][pmvC(v - 1)] +=  8.0 * s;
      B[v][pmvC(v + 1)] += -8.0 * s;
      B[v][pmvC(v + 2)] +=  s;
    }
    for (int v = 0; v < 13; ++v)
      for (int k = 0; k < 9; ++k){
        int c = v - 4 + k;
        if (c >= 0 && c < 13){
          double m = 0.0;
          for (int j = 0; j < 13; ++j) m += B[v][j] * B[j][c];
          t.z2[v][k] = (float)(0.1 * m);       // KV folded
          t.z1[v][k] = (float)B[v][c];
        }
      }
  }
  return t;
}
__constant__ STab cT = makeTab();

typedef short bf16x8 __attribute__((ext_vector_type(8)));
typedef float f32x4 __attribute__((ext_vector_type(4)));

DEVFN int pmh(int r){ return r < 0 ? r + 2 : (r > HH - 1 ? r - 2 : r); }
DEVFN int pmv(int r){ return r < 0 ? r + 2 : (r > VV - 1 ? r - 2 : r); }
DEVFN float latOf(int h){ return (90.0f - (float)(h + 1) * (180.0f / 33.0f)) * 0.017453292519943295f; }
DEVFN float avoid_inf(float t){
  if (t == 0.0f) t = 0.1f;
  if (fabsf(t) < 1.0f) t = copysignf(1.0f, t);
  return t;
}
DEVFN unsigned short f2bf(float f){
  unsigned u = __float_as_uint(f);
  unsigned r = (u + 0x7fffu + ((u >> 16) & 1u)) >> 16;
  return (unsigned short)r;
}

// ---- x-direction stencils via cross-lane shuffle of the central value ----
// w == lane (64-wide wave, h wave-uniform); periodic wrap == wave width.
DEVFN float dxSh(float c0, int w, float invpx){
  float m2 = __shfl(c0, (w + 62) & 63, 64);
  float m1 = __shfl(c0, (w + 63) & 63, 64);
  float p1 = __shfl(c0, (w + 1) & 63, 64);
  float p2 = __shfl(c0, (w + 2) & 63, 64);
  return (m2 - 8.f * m1 + 8.f * p1 - p2) * (1.f / 12.f) * invpx;
}
DEVFN float dxxSh(float c0, int w, float invpx){
  float m4 = __shfl(c0, (w + 60) & 63, 64);
  float m3 = __shfl(c0, (w + 61) & 63, 64);
  float m2 = __shfl(c0, (w + 62) & 63, 64);
  float m1 = __shfl(c0, (w + 63) & 63, 64);
  float p1 = __shfl(c0, (w + 1) & 63, 64);
  float p2 = __shfl(c0, (w + 2) & 63, 64);
  float p3 = __shfl(c0, (w + 3) & 63, 64);
  float p4 = __shfl(c0, (w + 4) & 63, 64);
  float s = m4 - 16.f * m3 + 64.f * m2 + 16.f * m1 - 130.f * c0
          + 16.f * p1 + 64.f * p2 - 16.f * p3 + p4;
  return s * (1.f / 144.f) * invpx * invpx;
}

// ---- fused (d, d2) table stencils; reuse central register for k=4 ----
DEVFN void dyPair(const float* __restrict__ F, const float* __restrict__ c1,
                  const float* __restrict__ c2, int bvbase, int h, int w, float cen,
                  float& dy, float& dyy){
  dy = 0.f; dyy = 0.f;
  #pragma unroll
  for (int k = 0; k < 9; ++k){
    int rr = h - 4 + k; rr = rr < 0 ? 0 : (rr > 31 ? 31 : rr);
    float val = (k == 4) ? cen : F[bvbase + rr * 64 + w];
    dy  = fmaf(c1[k], val, dy);
    dyy = fmaf(c2[k], val, dyy);
  }
}
DEVFN void dzPair(const float* __restrict__ F, const float* __restrict__ c1,
                  const float* __restrict__ c2, int bbase, int v, int hw, float cen,
                  float& dz, float& dzz){
  dz = 0.f; dzz = 0.f;
  #pragma unroll
  for (int k = 0; k < 9; ++k){
    int rr = v - 4 + k; rr = rr < 0 ? 0 : (rr > 12 ? 12 : rr);
    float val = (k == 4) ? cen : F[bbase + rr * 2048 + hw];
    dz  = fmaf(c1[k], val, dz);
    dzz = fmaf(c2[k], val, dzz);
  }
}

// ---- reductions ----
DEVFN float waveRedSum(float v){ for (int o = 32; o; o >>= 1) v += __shfl_down(v, o, 64); return v; }
DEVFN float waveRedMin(float v){ for (int o = 32; o; o >>= 1) v = fminf(v, __shfl_down(v, o, 64)); return v; }
DEVFN float waveRedMax(float v){ for (int o = 32; o; o >>= 1) v = fmaxf(v, __shfl_down(v, o, 64)); return v; }

template<int OP, int NWV>
static __device__ float blockRedN(float v){
  __shared__ float s[NWV];
  v = OP == 0 ? waveRedSum(v) : OP == 1 ? waveRedMin(v) : waveRedMax(v);
  int lane = threadIdx.x & 63, wid = threadIdx.x >> 6;
  __syncthreads();
  if (lane == 0) s[wid] = v;
  __syncthreads();
  float r = s[0];
  #pragma unroll
  for (int k = 1; k < NWV; ++k)
    r = OP == 0 ? r + s[k] : OP == 1 ? fminf(r, s[k]) : fmaxf(r, s[k]);
  return r;
}

struct GB { const float* g[5]; const float* b[5]; };

// ================= launch 1: transpose x + pack both weights =================
__global__ void __launch_bounds__(256) pre_k(const float* __restrict__ x,
    const float* __restrict__ w1, const float* __restrict__ w2,
    unsigned short* __restrict__ XT, unsigned short* __restrict__ wp1,
    unsigned short* __restrict__ wp2)
{
  int blk = blockIdx.x, t = threadIdx.x;
  if (blk < 1024){
    __shared__ float tile[16 * 68];
    int zz = blk >> 8, rem = blk & 255;
    int b = rem >> 5, h = rem & 31;
    for (int p = zz * 4; p < zz * 4 + 4; ++p){
      int cbase = p * 16;
      __syncthreads();
      {
        int cl = t >> 4, w4 = (t & 15) * 4;
        float4 v = *(const float4*)(x + (((size_t)(b * 256 + cbase + cl) * 32 + h) * 64 + w4));
        tile[cl * 68 + w4 + 0] = v.x; tile[cl * 68 + w4 + 1] = v.y;
        tile[cl * 68 + w4 + 2] = v.z; tile[cl * 68 + w4 + 3] = v.w;
      }
      __syncthreads();
      {
        int w = t >> 2, c4 = (t & 3) * 4;
        ushort4 o;
        o.x = f2bf(tile[(c4 + 0) * 68 + w]);
        o.y = f2bf(tile[(c4 + 1) * 68 + w]);
        o.z = f2bf(tile[(c4 + 2) * 68 + w]);
        o.w = f2bf(tile[(c4 + 3) * 68 + w]);
        *(ushort4*)(XT + (((size_t)(b * 32 + h) * 64 + w) * 256 + cbase + c4)) = o;
      }
    }
  } else {
    const int T1 = 9 * 80 * 256;
    const int T2 = 9 * 256 * 96;
    int idx = (blk - 1024) * 256 + t;
    if (idx < T1){
      int dir = idx / (80 * 256);
      int r = idx - dir * (80 * 256);
      int co = r / 256, ci = r - co * 256;
      float v = (co < 65) ? w1[((size_t)(co * 256 + ci)) * 9 + dir] : 0.f;
      wp1[idx] = f2bf(v);
    } else if (idx < T1 + T2){
      int j = idx - T1;
      int dir = j / (256 * 96);
      int r = j - dir * (256 * 96);
      int co = r / 96, ci = r - co * 96;
      float v = (ci < 65) ? w2[((size_t)(co * 65 + ci)) * 9 + dir] : 0.f;
      wp2[j] = f2bf(v);
    }
  }
}

// ================= conv via MFMA; 32-pixel blocks; BN partials in epilogue =================
template<int CIT, int CIL, int CO, int COp, int NW, int MF, int SWZ>
__global__ void __launch_bounds__(NW * 64) conv_mfma_k(
    const unsigned short* __restrict__ XT, const unsigned short* __restrict__ Wp,
    const float* __restrict__ bias, float* __restrict__ out, float* __restrict__ bnp)
{
  __shared__ __align__(16) unsigned short Xl[3 * 34 * CIL];
  const int C8 = CIL / 8;
  int tid = threadIdx.x;
  int bx = blockIdx.x, b = blockIdx.y;
  int h = bx >> 1, p0 = (bx & 1) << 5;
  int bh = b * 64 + bx;
  int wid = tid >> 6, lane = tid & 63;
  int l15 = lane & 15, q = lane >> 4;

  f32x4 acc[MF][2];
  #pragma unroll
  for (int mf = 0; mf < MF; ++mf)
    #pragma unroll
    for (int nf = 0; nf < 2; ++nf){ f32x4 z = {0.f, 0.f, 0.f, 0.f}; acc[mf][nf] = z; }

  for (int cp = 0; cp < CIT / CIL; ++cp){
    if (cp) __syncthreads();
    for (int idx = tid; idx < 3 * 34 * C8; idx += NW * 64){
      int r = idx / (34 * C8);
      int rest = idx - r * (34 * C8);
      int j = rest / C8;
      int c8 = rest - j * C8;
      int hh = h + r - 1;
      int gw = p0 - 1 + j;
      uint4 val = make_uint4(0, 0, 0, 0);
      if (hh >= 0 && hh < 32 && gw >= 0 && gw < 64)
        val = *(const uint4*)(XT + (((size_t)(b * 32 + hh) * 64 + gw) * CIT + cp * CIL + c8 * 8));
      int dst = (r * 34 + j) * CIL + ((c8 * 8) ^ ((j & SWZ) << 3));
      *(uint4*)(Xl + dst) = val;
    }
    __syncthreads();

    for (int dir = 0; dir < 9; ++dir){
      int dy = dir / 3, dx = dir - dy * 3;
      #pragma unroll
      for (int kc = 0; kc < CIL / 32; ++kc){
        int kb = kc * 32 + q * 8;
        bf16x8 a[MF];
        #pragma unroll
        for (int mf = 0; mf < MF; ++mf){
          int co = wid * (MF * 16) + mf * 16 + l15;
          a[mf] = *(const bf16x8*)(Wp + ((size_t)(dir * COp + co) * CIT + cp * CIL + kb));
        }
        #pragma unroll
        for (int nf = 0; nf < 2; ++nf){
          int j = nf * 16 + l15 + dx;
          bf16x8 bfrag = *(const bf16x8*)(Xl + ((dy * 34 + j) * CIL + (kb ^ ((j & SWZ) << 3))));
          #pragma unroll
          for (int mf = 0; mf < MF; ++mf)
            acc[mf][nf] = __builtin_amdgcn_mfma_f32_16x16x32_bf16(a[mf], bfrag, acc[mf][nf], 0, 0, 0);
        }
      }
    }
  }
  #pragma unroll
  for (int mf = 0; mf < MF; ++mf){
    #pragma unroll
    for (int r = 0; r < 4; ++r){
      int co = wid * (MF * 16) + mf * 16 + q * 4 + r;
      if (CO != COp && co >= CO) continue;
      float bv = bias[co];
      float sv = 0.f, sq = 0.f;
      #pragma unroll
      for (int nf = 0; nf < 2; ++nf){
        int pix = nf * 16 + l15;
        float val = acc[mf][nf][r] + bv;
        out[(size_t)(b * CO + co) * 2048 + h * 64 + p0 + pix] = val;
        sv += val; sq += val * val;
      }
      #pragma unroll
      for (int off = 8; off; off >>= 1){
        sv += __shfl_xor(sv, off, 16);
        sq += __shfl_xor(sq, off, 16);
      }
      if (l15 == 0){
        bnp[((size_t)co * 512 + bh) * 2]     = sv;
        bnp[((size_t)co * 512 + bh) * 2 + 1] = sq;
      }
    }
  }
}

// ================= prep: BN1 finalize (redundant) + field prep, XCD-swizzled =================
__global__ void __launch_bounds__(256) prep_k(const float* __restrict__ hb,
  const float* __restrict__ bnp1, GB gb,
  float* __restrict__ Fz, float* __restrict__ Fq, float* __restrict__ Fu,
  float* __restrict__ Fvf, float* __restrict__ Ft,
  float* __restrict__ zx, float* __restrict__ zy, float* __restrict__ zz,
  float* __restrict__ ux, float* __restrict__ vy, float* __restrict__ wv,
  float* __restrict__ partS)
{
  __shared__ float As[65], Bs[65];
  int blk = blockIdx.x, t = threadIdx.x;
  {
    int wvid = t >> 6, lane = t & 63;
    for (int ch = wvid; ch < 65; ch += 4){
      const float4* pp = (const float4*)(bnp1 + (size_t)ch * 1024) + lane * 4;
      float s = 0.f, sq = 0.f;
      #pragma unroll
      for (int k = 0; k < 4; ++k){ float4 v = pp[k]; s += v.x + v.z; sq += v.y + v.w; }
      s = waveRedSum(s); sq = waveRedSum(sq);
      if (!lane){
        float m = s * (1.f / 16384.f);
        float var = sq * (1.f / 16384.f) - m * m;
        float rstd = rsqrtf(var + 1e-5f);
        int f = ch / 13, k = ch - f * 13;
        float g = gb.g[f][k], bbv = gb.b[f][k];
        As[ch] = g * rstd; Bs[ch] = bbv - m * g * rstd;
      }
    }
  }
  __syncthreads();

  int part = blk >> 6;
  int chunk = blk & 63;
  int b = chunk & 7;                       // XCD-aligned
  int p = ((chunk >> 3) << 8) | t;
  int h = p >> 6, w = p & 63;
  int hbase = b * 65 * NPLANE;
  auto hn = [&](int ch, int hh, int ww)->float {
    return hb[hbase + ch * 2048 + hh * 64 + ww] * As[ch] + Bs[ch];
  };
  int fb = (b * 13) * 2048 + p;
  float lat = latOf(h);
  float invpx = 1.0f / (PXCc * cosf(lat));
  int hm2 = pmh(h - 2), hm1 = pmh(h - 1), hp1 = pmh(h + 1), hp2 = pmh(h + 2);
  float fmn = FBIG, fmx = -FBIG, fsm = 0.f, smn = FBIG, smx = -FBIG;
  if (part < 5){
    int ch0 = part * 13;
    float c[13];
    #pragma unroll
    for (int v = 0; v < 13; ++v) c[v] = hn(ch0 + v, h, w);
    float* Fdst = part == 0 ? Fz : part == 1 ? Fq : part == 2 ? Fu : part == 3 ? Fvf : Ft;
    #pragma unroll
    for (int v = 0; v < 13; ++v) Fdst[fb + v * 2048] = c[v];
    if (part == 0){
      #pragma unroll
      for (int v = 0; v < 13; ++v){
        zz[fb + v * 2048] = (-c[pmv(v - 2)] + 8.f * c[pmv(v - 1)] - 8.f * c[pmv(v + 1)] + c[pmv(v + 2)]) * cZI[v];
        float zxv = dxSh(c[v], w, invpx);
        float zyv = (-hn(v, hm2, w) + 8.f * hn(v, hm1, w) - 8.f * hn(v, hp1, w) + hn(v, hp2, w)) * (1.f / 12.f) * (1.f / PYc);
        zx[fb + v * 2048] = zxv; zy[fb + v * 2048] = zyv;
      }
    }
    if (part == 2){
      #pragma unroll
      for (int v = 0; v < 13; ++v)
        ux[fb + v * 2048] = dxSh(c[v], w, invpx);
    }
    if (part == 3){
      #pragma unroll
      for (int v = 0; v < 13; ++v){
        float vyv = (-hn(39 + v, hm2, w) + 8.f * hn(39 + v, hm1, w) - 8.f * hn(39 + v, hp1, w) + hn(39 + v, hp2, w)) * (1.f / 12.f) * (1.f / PYc);
        vy[fb + v * 2048] = vyv;
      }
    }
    if (part == 4){
      #pragma unroll
      for (int v = 0; v < 13; ++v){
        float tcc = c[v] - 273.15f;
        float arg = 17.67f * tcc / avoid_inf(tcc + 243.5f);
        smn = fminf(smn, arg); smx = fmaxf(smx, arg);
      }
    }
    #pragma unroll
    for (int v = 0; v < 13; ++v){ fmn = fminf(fmn, c[v]); fmx = fmaxf(fmx, c[v]); fsm += c[v]; }
  } else {
    float cum = 0.f;
    #pragma unroll
    for (int v = 0; v < 13; ++v){
      float uc = hn(26 + v, h, w);
      float uxv = dxSh(uc, w, invpx);
      float vyv = (-hn(39 + v, hm2, w) + 8.f * hn(39 + v, hm1, w) - 8.f * hn(39 + v, hp1, w) + hn(39 + v, hp2, w)) * (1.f / 12.f) * (1.f / PYc);
      cum += cDZ[v] * (uxv + vyv);
      wv[fb + v * 2048] = -cum;
    }
  }
  float* pb = partS + blk * 17;
  float r;
  r = blockRedN<1,4>(smn); if (!t) pb[0] = r;
  r = blockRedN<2,4>(smx); if (!t) pb[1] = r;
  #pragma unroll
  for (int f = 0; f < 5; ++f){
    r = blockRedN<1,4>(part == f ? fmn : FBIG);  if (!t) pb[2 + f * 3] = r;
    r = blockRedN<2,4>(part == f ? fmx : -FBIG); if (!t) pb[3 + f * 3] = r;
    r = blockRedN<0,4>(part == f ? fsm : 0.f);   if (!t) pb[4 + f * 3] = r;
  }
}

// ===== merged RK stage: XCD swizzle + composed tables + shuffle x-stencils =====
template<int STAGE>
__global__ void __launch_bounds__(256) stage_k(
  const float* __restrict__ U, const float* __restrict__ Vf, const float* __restrict__ T,
  const float* __restrict__ Fu, const float* __restrict__ Fvf, const float* __restrict__ Ft,
  const float* __restrict__ Fq,
  const float* __restrict__ ux, const float* __restrict__ vy,
  const float* __restrict__ zx, const float* __restrict__ zy,
  const float* __restrict__ wv, const float* __restrict__ zz,
  const float* __restrict__ partS,
  float* C0, float* prr,
  float* Uo, float* Vo, float* To,
  float* duA, float* dvA, float* dtA, float* k4t, float* qtA,
  float* pduv, float* pdt, float* pqt, float cnext)
{
  float ss = 0.f, off = 0.f;
  if (STAGE == 1){
    int tt = threadIdx.x;
    float v0 = partS[tt * 17], v1 = partS[tt * 17 + 1];
    if (tt < 128){
      v0 = fminf(v0, partS[(tt + 256) * 17]);
      v1 = fmaxf(v1, partS[(tt + 256) * 17 + 1]);
    }
    float smn = blockRedN<1,4>(v0);
    float smx = blockRedN<2,4>(v1);
    ss = (3.01f + 3.47f) / (smx - smn);
    off = -3.47f - smn * ss;
  }
  int blk = blockIdx.x, t = threadIdx.x;
  int b = blk & 7;
  int rest = blk >> 3;
  int v = rest % 13;
  int hg = rest / 13;
  int h = (hg << 2) | (t >> 6);
  int w = t & 63;
  int bv = b * 13 + v;
  int bvbase = bv * 2048;
  int bbase = b * 13 * 2048;
  int hw = h * 64 + w;
  int i = bvbase + hw;
  float lat = latOf(h);
  float invpx = 1.0f / (PXCc * cosf(lat));
  float fcor = 2.0f * OMEGAc * sinf(lat);
  float wvi = wv[i];
  float Ui = U[i], Vi = Vf[i], Ti = T[i];
  float Fui = (STAGE == 1) ? Ui : Fu[i];
  float Fvi = (STAGE == 1) ? Vi : Fvf[i];

  const float* y1 = cT.y1[h];
  const float* y2 = cT.y2[h];
  const float* z1 = cT.z1[v];
  const float* z2 = cT.z2[v];

  // ---- u tendency ----
  float dyU, dyyU, dzU, dzzU;
  dyPair(U, y1, y2, bvbase, h, w, Ui, dyU, dyyU);
  dzPair(U, z1, z2, bbase, v, hw, Ui, dzU, dzzU);
  float mixU = KHc * dxxSh(Ui, w, invpx) + dyyU + dzzU;
  float ku = -Ui * ux[i] - Vi * dyU - wvi * dzU + fcor * Vi - zx[i] + mixU;

  // ---- v tendency ----
  float dyVd, dyyV, dzV, dzzV;
  dyPair(Vf, y1, y2, bvbase, h, w, Vi, dyVd, dyyV);
  dzPair(Vf, z1, z2, bbase, v, hw, Vi, dzV, dzzV);
  float dxV = dxSh(Vi, w, invpx);
  float mixV = KHc * dxxSh(Vi, w, invpx) + dyyV + dzzV;
  float kv = -Ui * dxV - Vi * vy[i] - wvi * dzV - fcor * Ui - zy[i] + mixV;

  // ---- C0 ----
  float C0i;
  if (STAGE == 1){
    float zzi = zz[i], qi = Fq[i];
    float rho = -1.0f / avoid_inf(zzi);
    float p = rho * R_GASc * Ti;               // Ti == Ft at stage 1
    float tcc = Ti - 273.15f;
    float arg = 17.67f * tcc / avoid_inf(tcc + 243.5f);
    float es = 6.112f * expf(arg * ss + off) * 100.0f;
    float qs = fmaxf(0.622f * es / avoid_inf(p - 0.378f * es), 1e-6f);
    float rh = qi / avoid_inf(qs);
    float rate = (rh > PTHc) ? (qi - PTHc * qs) * (1.0f / DT) : 0.0f;
    prr[i] = rate;
    C0i = -(L_Vc + 1.0f) * zzi * wvi * (1.0f / C_Pc) + rate * (L_Vc / C_Pc);
    C0[i] = C0i;
  } else {
    C0i = C0[i];
  }

  // ---- t tendency ----
  float dyT, dyyT, dzT, dzzT;
  dyPair(T, y1, y2, bvbase, h, w, Ti, dyT, dyyT);
  dzPair(T, z1, z2, bbase, v, hw, Ti, dzT, dzzT);
  float dxT = dxSh(Ti, w, invpx);
  float mixT = KHc * dxxSh(Ti, w, invpx) + dyyT + dzzT;
  float ta = Ti + 273.15f;
  float t2 = ta * ta;
  float ta5 = t2 * t2 * ta;
  float rc = cRC[v] * ta5;
  float kt = C0i - Fui * dxT - Fvi * dyT - wvi * dzT + mixT + rc;

  if (STAGE == 1){ duA[i] = ku; dvA[i] = kv; dtA[i] = kt; }
  else if (STAGE < 4){ duA[i] += 2.f * ku; dvA[i] += 2.f * kv; dtA[i] += 2.f * kt; }
  else {
    float au = duA[i] + ku, av = dvA[i] + kv, at = dtA[i] + kt;
    duA[i] = au; dvA[i] = av; dtA[i] = at; k4t[i] = kt;
    float m0 = blockRedN<1,4>(au), m1 = blockRedN<2,4>(au);
    float m2 = blockRedN<1,4>(av), m3 = blockRedN<2,4>(av);
    float m4 = blockRedN<1,4>(at), m5 = blockRedN<2,4>(at);
    if (!t){
      float* pp = pduv + blk * 4;
      pp[0] = m0; pp[1] = m1; pp[2] = m2; pp[3] = m3;
      pdt[blk * 2] = m4; pdt[blk * 2 + 1] = m5;
    }
  }
  if (STAGE < 4){
    float Fti = (STAGE == 1) ? Ti : Ft[i];
    Uo[i] = Fui + cnext * ku;
    Vo[i] = Fvi + cnext * kv;
    To[i] = Fti + cnext * kt;
  }

  if (STAGE == 2){
    float Qc = Fq[i];
    float dyQ, dyyQ, dzQ, dzzQ;
    dyPair(Fq, y1, y2, bvbase, h, w, Qc, dyQ, dyyQ);
    dzPair(Fq, z1, z2, bbase, v, hw, Qc, dzQ, dzzQ);
    float mixQ = KHc * dxxSh(Qc, w, invpx) + dyyQ + dzzQ;
    float qtv = -Fui * dxSh(Qc, w, invpx) - Fvi * dyQ - wvi * dzQ + mixQ - prr[i];
    qtA[i] = qtv;
    float m0 = blockRedN<1,4>(qtv), m1 = blockRedN<2,4>(qtv);
    if (!t){ pqt[blk * 2] = m0; pqt[blk * 2 + 1] = m1; }
  }
}

__global__ void __launch_bounds__(64) zt_k(const float* __restrict__ k4t, float* __restrict__ zt, float* __restrict__ pmm)
{
  int blk = blockIdx.x;
  int b = blk & 7;
  int p = ((blk >> 3) << 6) + threadIdx.x;
  int fb = b * 13 * 2048 + p;
  float cum = 0.f, mn = FBIG, mx = -FBIG;
  #pragma unroll
  for (int v = 0; v < 13; ++v){
    cum += cZW[v] * k4t[fb + v * 2048];
    zt[fb + v * 2048] = cum;
    mn = fminf(mn, cum); mx = fmaxf(mx, cum);
  }
  mn = waveRedMin(mn); mx = waveRedMax(mx);
  if (!threadIdx.x){ pmm[blk * 2] = mn; pmm[blk * 2 + 1] = mx; }
}

// ===== fused: redundant sc2 finalize + outmid (LDS tile) + bf16 transpose out =====
__global__ void __launch_bounds__(256) outmid_fused_k(
  const float* __restrict__ hb,
  const float* __restrict__ Fz, const float* __restrict__ Fq, const float* __restrict__ Fu,
  const float* __restrict__ Fvf, const float* __restrict__ Ft,
  const float* __restrict__ ztA, const float* __restrict__ qtA,
  const float* __restrict__ duA, const float* __restrict__ dvA, const float* __restrict__ dtA,
  const float* __restrict__ coef, const float* __restrict__ partS,
  const float* __restrict__ pduv, const float* __restrict__ pdt,
  const float* __restrict__ pqt, const float* __restrict__ pzt,
  unsigned short* __restrict__ MT)
{
  __shared__ float tileBig[65 * 66];
  int blk = blockIdx.x, t = threadIdx.x;

  float fmn[5] = {FBIG, FBIG, FBIG, FBIG, FBIG};
  float fmx[5] = {-FBIG, -FBIG, -FBIG, -FBIG, -FBIG};
  float fsm[5] = {0.f, 0.f, 0.f, 0.f, 0.f};
  #pragma unroll 1
  for (int r0 = t; r0 < 384; r0 += 256){
    const float* pr = partS + r0 * 17;
    #pragma unroll
    for (int f = 0; f < 5; ++f){
      fmn[f] = fminf(fmn[f], pr[2 + f * 3]);
      fmx[f] = fmaxf(fmx[f], pr[3 + f * 3]);
      fsm[f] += pr[4 + f * 3];
    }
  }
  #pragma unroll
  for (int f = 0; f < 5; ++f){
    fmn[f] = blockRedN<1,4>(fmn[f]);
    fmx[f] = blockRedN<2,4>(fmx[f]);
    fsm[f] = blockRedN<0,4>(fsm[f]);
  }
  float dumn = FBIG, dumx = -FBIG, dvmn = FBIG, dvmx = -FBIG, dtmn = FBIG, dtmx = -FBIG;
  float qmn = FBIG, qmx = -FBIG;
  #pragma unroll 1
  for (int r0 = t; r0 < 832; r0 += 256){
    dumn = fminf(dumn, pduv[r0 * 4]);     dumx = fmaxf(dumx, pduv[r0 * 4 + 1]);
    dvmn = fminf(dvmn, pduv[r0 * 4 + 2]); dvmx = fmaxf(dvmx, pduv[r0 * 4 + 3]);
    dtmn = fminf(dtmn, pdt[r0 * 2]);      dtmx = fmaxf(dtmx, pdt[r0 * 2 + 1]);
    qmn = fminf(qmn, pqt[r0 * 2]);        qmx = fmaxf(qmx, pqt[r0 * 2 + 1]);
  }
  float zmn = pzt[t * 2], zmx = pzt[t * 2 + 1];
  dumn = blockRedN<1,4>(dumn); dumx = blockRedN<2,4>(dumx);
  dvmn = blockRedN<1,4>(dvmn); dvmx = blockRedN<2,4>(dvmx);
  dtmn = blockRedN<1,4>(dtmn); dtmx = blockRedN<2,4>(dtmx);
  qmn = blockRedN<1,4>(qmn);   qmx = blockRedN<2,4>(qmx);
  zmn = blockRedN<1,4>(zmn);   zmx = blockRedN<2,4>(zmx);

  float scf[5], off2[5];
  {
    float rmn[5] = {zmn, qmn, dumn, dvmn, dtmn};
    float rmx[5] = {zmx, qmx, dumx, dvmx, dtmx};
    float cfs[5] = {DT, DT, DT / 6.f, DT / 6.f, DT / 6.f};
    #pragma unroll
    for (int f = 0; f < 5; ++f){
      float mnf = fmn[f], mef = fsm[f] * (1.0f / (float)NF), mxf = fmx[f];
      float aa = (mnf - mef) * 0.05f, b2 = (mxf - mef) * 0.05f;
      float cf = cfs[f];
      float dmn = rmn[f] * cf, dmx = rmx[f] * cf;
      float s = (b2 - aa) / (dmx - dmn);
      scf[f] = s * cf; off2[f] = aa - dmn * s;
    }
  }

  int b = blk & 7, h = blk >> 3;
  #pragma unroll 1
  for (int idx = t; idx < 65 * 64; idx += 256){
    int c = idx >> 6, w = idx & 63;
    int f = c / 13, v = c - f * 13;
    int fi = (b * 13 + v) * 2048 + h * 64 + w;
    const float *Fp, *Rp;
    switch (f){
      case 0: Fp = Fz;  Rp = ztA; break;
      case 1: Fp = Fq;  Rp = qtA; break;
      case 2: Fp = Fu;  Rp = duA; break;
      case 3: Fp = Fvf; Rp = dvA; break;
      default: Fp = Ft; Rp = dtA; break;
    }
    float phys = Fp[fi] + Rp[fi] * scf[f] + off2[f];
    float cf = coef[c * 2048 + h * 64 + w];
    float hbv = hb[((size_t)(b * 65 + c)) * 2048 + h * 64 + w];
    tileBig[c * 66 + w] = cf * phys + (1.0f - cf) * hbv;
  }
  __syncthreads();
  #pragma unroll 1
  for (int ph = 0; ph < 6; ++ph){
    int cbase = ph * 16;
    int w = t >> 2, c4 = (t & 3) * 4;
    int c0 = cbase + c4;
    ushort4 o;
    o.x = (c0 + 0 < 65) ? f2bf(tileBig[(c0 + 0) * 66 + w]) : (unsigned short)0;
    o.y = (c0 + 1 < 65) ? f2bf(tileBig[(c0 + 1) * 66 + w]) : (unsigned short)0;
    o.z = (c0 + 2 < 65) ? f2bf(tileBig[(c0 + 2) * 66 + w]) : (unsigned short)0;
    o.w = (c0 + 3 < 65) ? f2bf(tileBig[(c0 + 3) * 66 + w]) : (unsigned short)0;
    *(ushort4*)(MT + (((size_t)(b * 32 + h) * 64 + w) * 96 + c0)) = o;
  }
}

// ===== final: redundant BN2 finalize + apply BN + residual =====
__global__ void __launch_bounds__(256) final_k(float* __restrict__ y, const float* __restrict__ x,
  const float* __restrict__ bnp2, const float* __restrict__ gblk, const float* __restrict__ bblk)
{
  int blk = blockIdx.x, t = threadIdx.x;
  int c = (blk >> 1) & 255;
  float4 pv = ((const float4*)(bnp2 + (size_t)c * 1024))[t];
  float s = pv.x + pv.z, sq = pv.y + pv.w;
  s = blockRedN<0,4>(s); sq = blockRedN<0,4>(sq);
  float m = s * (1.0f / 16384.0f);
  float var = sq * (1.0f / 16384.0f) - m * m;
  float rstd = rsqrtf(var + 1e-5f);
  float a = gblk[c] * rstd, bb = bblk[c] - m * gblk[c] * rstd;
  int e4 = blk * 256 + t;
  float4 v = ((const float4*)y)[e4];
  float4 xv = ((const float4*)x)[e4];
  v.x = v.x * a + bb + xv.x;
  v.y = v.y * a + bb + xv.y;
  v.z = v.z * a + bb + xv.z;
  v.w = v.w * a + bb + xv.w;
  ((float4*)y)[e4] = v;
}

extern "C" void kernel_launch(void* const* d_in, const int* in_sizes, int n_in,
                              void* d_out, int out_size, void* d_ws, size_t ws_size,
                              hipStream_t stream)
{
  (void)in_sizes; (void)n_in; (void)out_size; (void)ws_size;
  const float* x        = (const float*)d_in[0];
  const float* w_norm   = (const float*)d_in[1];
  const float* b_norm   = (const float*)d_in[2];
  const float* w_innorm = (const float*)d_in[3];
  const float* b_innorm = (const float*)d_in[4];
  const float* coef     = (const float*)d_in[5];
  GB gb;
  for (int f = 0; f < 5; ++f){
    gb.g[f] = (const float*)d_in[6 + 2 * f];
    gb.b[f] = (const float*)d_in[7 + 2 * f];
  }
  const float* gblk = (const float*)d_in[16];
  const float* bblk = (const float*)d_in[17];
  float* yout = (float*)d_out;

  float* ws = (float*)d_ws;
  size_t off = 0;
  auto alloc = [&](size_t n){ float* p = ws + off; off += n; return p; };
  float* hb  = alloc(NHB);
  float* Fz  = alloc(NF); float* Fq  = alloc(NF); float* Fu  = alloc(NF);
  float* Fvf = alloc(NF); float* Ft  = alloc(NF);
  float* zx  = alloc(NF); float* zy  = alloc(NF); float* zz  = alloc(NF);
  float* ux  = alloc(NF); float* vy  = alloc(NF); float* wvel = alloc(NF);
  float* C0  = alloc(NF); float* prr = alloc(NF);
  float* Ua  = alloc(NF); float* Ub  = alloc(NF); float* Va  = alloc(NF); float* Vb = alloc(NF);
  float* Ta  = alloc(NF); float* Tb  = alloc(NF);
  float* duA = alloc(NF); float* dvA = alloc(NF); float* dtA = alloc(NF);
  float* k4t = alloc(NF); float* ztA = alloc(NF); float* qtA = alloc(NF);
  float* part1 = alloc(384 * 17 + 4);
  float* pduv = alloc(832 * 4); float* pdt = alloc(832 * 2);
  float* pqt  = alloc(832 * 2); float* pzt = alloc(256 * 2);
  float* bnp1 = alloc(65 * 512 * 2);
  float* bnp2 = alloc(256 * 512 * 2);
  float* Wp1f = alloc(9 * 80 * 256 / 2);
  float* Wp2f = alloc(9 * 256 * 96 / 2);
  unsigned short* Wp1 = (unsigned short*)Wp1f;
  unsigned short* Wp2 = (unsigned short*)Wp2f;
  // XT bf16 (8.39 MB) aliases Ua..qtA; dead after conv1, before stage1 writes Ua.
  unsigned short* XT = (unsigned short*)Ua;
  // MT bf16 (3.15 MB) aliases C0,prr,Ua,Ub — all dead after stage4; outmid reads none.
  unsigned short* MT = (unsigned short*)C0;

  // 1. transpose x + pack both weights
  pre_k<<<2608, 256, 0, stream>>>(x, w_norm, w_innorm, XT, Wp1, Wp2);
  // 2. conv1 (bf16 MFMA, BN1 partials in epilogue)
  conv_mfma_k<256, 128, 65, 80, 5, 1, 7><<<dim3(64, 8), 5 * 64, 0, stream>>>(XT, Wp1, b_norm, hb, bnp1);
  // 3. prep (redundant BN1 finalize + field split, XCD-swizzled, shuffle x-stencils)
  prep_k<<<384, 256, 0, stream>>>(hb, bnp1, gb, Fz, Fq, Fu, Fvf, Ft, zx, zy, zz, ux, vy, wvel, part1);
  // 4-7. RK stages (XCD swizzle, composed tables, shuffle x-stencils)
  stage_k<1><<<NF / 256, 256, 0, stream>>>(Fu, Fvf, Ft, Fu, Fvf, Ft, Fq, ux, vy, zx, zy, wvel, zz, part1,
      C0, prr, Ua, Va, Ta, duA, dvA, dtA, k4t, qtA, pduv, pdt, pqt, 0.5f * DT);
  stage_k<2><<<NF / 256, 256, 0, stream>>>(Ua, Va, Ta, Fu, Fvf, Ft, Fq, ux, vy, zx, zy, wvel, zz, part1,
      C0, prr, Ub, Vb, Tb, duA, dvA, dtA, k4t, qtA, pduv, pdt, pqt, 0.5f * DT);
  stage_k<3><<<NF / 256, 256, 0, stream>>>(Ub, Vb, Tb, Fu, Fvf, Ft, Fq, ux, vy, zx, zy, wvel, zz, part1,
      C0, prr, Ua, Va, Ta, duA, dvA, dtA, k4t, qtA, pduv, pdt, pqt, DT);
  stage_k<4><<<NF / 256, 256, 0, stream>>>(Ua, Va, Ta, Fu, Fvf, Ft, Fq, ux, vy, zx, zy, wvel, zz, part1,
      C0, prr, Ub, Vb, Tb, duA, dvA, dtA, k4t, qtA, pduv, pdt, pqt, 0.f);
  // 8. z-tendency integral (XCD-swizzled)
  zt_k<<<256, 64, 0, stream>>>(k4t, ztA, pzt);
  // 9. fused finalize + outmid + bf16 transpose (XCD-swizzled)
  outmid_fused_k<<<256, 256, 0, stream>>>(hb, Fz, Fq, Fu, Fvf, Ft, ztA, qtA, duA, dvA, dtA,
      coef, part1, pduv, pdt, pqt, pzt, MT);
  // 10. conv2 (BN2 partials in epilogue)
  conv_mfma_k<96, 96, 256, 256, 8, 2, 3><<<dim3(64, 8), 8 * 64, 0, stream>>>(MT, Wp2, b_innorm, yout, bnp2);
  // 11. redundant BN2 finalize + apply + residual
  final_k<<<4096, 256, 0, stream>>>(yout, x, bnp2, gblk, bblk);
}